// Round 9
// baseline (243.681 us; speedup 1.0000x reference)
//
#include <hip/hip_runtime.h>
#include <hip/hip_bf16.h>

#define BATCH 4
#define SEQ   4096
#define DIM   1024
#define RANK  64

typedef __attribute__((ext_vector_type(8))) short short8;
typedef __attribute__((ext_vector_type(4))) short short4v;
typedef __attribute__((ext_vector_type(4))) float f32x4;

#define MFMA16(a,b,c) __builtin_amdgcn_mfma_f32_16x16x32_bf16((a),(b),(c),0,0,0)

// workspace layout (in shorts/bf16 elements)
#define XQ_OFF 0
#define XK_OFF (BATCH*SEQ*RANK)
#define VT_OFF (2*BATCH*SEQ*RANK)
#define VT_END (VT_OFF + BATCH*DIM*SEQ)          // 18,874,368 shorts
#define P_OFF  ((size_t)VT_END)
#define P_LEN  ((size_t)BATCH*SEQ*SEQ)           // 67,108,864 shorts (128MB)

__device__ __forceinline__ short f2b(float f) {
    __hip_bfloat16 h = __float2bfloat16(f);
    short s; __builtin_memcpy(&s, &h, sizeof(short));
    return s;
}
__device__ __forceinline__ float b2f(short s) {
    __hip_bfloat16 h; __builtin_memcpy(&h, &s, sizeof(short));
    return __bfloat162float(h);
}
__device__ __forceinline__ short8 cvt8(const float* __restrict__ p) {
    const float4 f0 = *reinterpret_cast<const float4*>(p);
    const float4 f1 = *reinterpret_cast<const float4*>(p + 4);
    short8 r;
    r[0]=f2b(f0.x); r[1]=f2b(f0.y); r[2]=f2b(f0.z); r[3]=f2b(f0.w);
    r[4]=f2b(f1.x); r[5]=f2b(f1.y); r[6]=f2b(f1.z); r[7]=f2b(f1.w);
    return r;
}
__device__ __forceinline__ void gld16(const short* g, short* l) {
    __builtin_amdgcn_global_load_lds(
        (const __attribute__((address_space(1))) void*)g,
        (__attribute__((address_space(3))) void*)l, 16, 0, 0);
}

// ---------------------------------------------------------------------------
// lr_cvt: xb = bf16(x); VOt = bf16(VO^T); Wb = bf16(concat(Q,K)).
// ---------------------------------------------------------------------------
__global__ __launch_bounds__(256) void lr_cvt(const float* __restrict__ x,
                                              const float* __restrict__ VO,
                                              const float* __restrict__ Qw,
                                              const float* __restrict__ Kw,
                                              short* __restrict__ xb,
                                              short* __restrict__ VOt,
                                              short* __restrict__ Wb)
{
    const int bid = blockIdx.x, tid = threadIdx.x;
    if (bid < 8192) {
        const size_t base = ((size_t)bid*256 + tid)*8;
        *reinterpret_cast<short8*>(xb + base) = cvt8(x + base);
    } else if (bid < 8448) {
        __shared__ short tr[64*68];
        const int bb = bid - 8192;
        const int dt = bb >> 4, et = bb & 15;
        const int d0 = dt*64, e0 = et*64;
        const int ein = tid & 63, din = tid >> 6;
        #pragma unroll
        for (int j = 0; j < 16; ++j) {
            const int dl = din + j*4;
            tr[ein*68 + dl] = f2b(VO[(size_t)(d0 + dl)*DIM + e0 + ein]);
        }
        __syncthreads();
        const int or_ = tid >> 4, oc = (tid & 15)*4;
        #pragma unroll
        for (int j = 0; j < 4; ++j) {
            const int el = or_ + j*16;
            short4v v;
            v[0]=tr[el*68+oc]; v[1]=tr[el*68+oc+1];
            v[2]=tr[el*68+oc+2]; v[3]=tr[el*68+oc+3];
            *reinterpret_cast<short4v*>(VOt + (size_t)(e0+el)*DIM + d0 + oc) = v;
        }
    } else {
        const int gid = (bid - 8448)*256 + tid;     // [0,16384)
        const int row = gid >> 7, c8 = (gid & 127)*8;
        const float* src = (row < 64 ? Qw + (size_t)row*DIM
                                     : Kw + (size_t)(row-64)*DIM) + c8;
        *reinterpret_cast<short8*>(Wb + (size_t)row*DIM + c8) = cvt8(src);
    }
}

// ---------------------------------------------------------------------------
// lr_proj2: D[t][r] = xb . Wb^T -> xq/xk bf16 [gt][64]. m97 structure.
// ---------------------------------------------------------------------------
__global__ __launch_bounds__(256, 4) void lr_proj2(const short* __restrict__ xb,
                                                   const short* __restrict__ Wb,
                                                   short* __restrict__ ws)
{
    __shared__ __align__(16) short As[128*64];
    __shared__ __align__(16) short Bs[128*64];
    const int t0 = blockIdx.x*128;
    const int tid = threadIdx.x, lane = tid & 63, w = tid >> 6;
    const int l15 = lane & 15, g = lane >> 4;
    const int wr = w >> 1, wc = w & 1;
    const short* Ab = xb + (size_t)t0*DIM;
    const short* Bb = Wb;
    const int srow = lane >> 3;
    const int skc  = ((lane & 7) ^ srow)*8;
    const int rx = l15 & 7;

    f32x4 acc[4][4] = {};
    #pragma unroll
    for (int j = 0; j < 4; ++j) {
        const int ch = 4*w + j, row = ch*8 + srow;
        gld16(Ab + (size_t)row*DIM + skc, &As[ch*512]);
        gld16(Bb + (size_t)row*DIM + skc, &Bs[ch*512]);
    }
    for (int kt = 0; kt < 16; ++kt) {
        __syncthreads();
        #pragma unroll
        for (int ks = 0; ks < 2; ++ks) {
            short8 af[4], bfr[4];
            #pragma unroll
            for (int mr = 0; mr < 4; ++mr)
                af[mr] = *reinterpret_cast<const short8*>(
                    &As[(wr*64 + mr*16 + l15)*64 + ((ks*4 + g) ^ rx)*8]);
            #pragma unroll
            for (int ct = 0; ct < 4; ++ct)
                bfr[ct] = *reinterpret_cast<const short8*>(
                    &Bs[(wc*64 + ct*16 + l15)*64 + ((ks*4 + g) ^ rx)*8]);
            #pragma unroll
            for (int mr = 0; mr < 4; ++mr)
                #pragma unroll
                for (int ct = 0; ct < 4; ++ct)
                    acc[mr][ct] = MFMA16(af[mr], bfr[ct], acc[mr][ct]);
        }
        if (kt < 15) {
            __syncthreads();
            const int k0 = (kt + 1)*64;
            #pragma unroll
            for (int j = 0; j < 4; ++j) {
                const int ch = 4*w + j, row = ch*8 + srow;
                gld16(Ab + (size_t)row*DIM + k0 + skc, &As[ch*512]);
                gld16(Bb + (size_t)row*DIM + k0 + skc, &Bs[ch*512]);
            }
        }
    }
    short* xqp = ws + XQ_OFF;
    short* xkp = ws + XK_OFF;
    #pragma unroll
    for (int mr = 0; mr < 4; ++mr)
        #pragma unroll
        for (int rr = 0; rr < 4; ++rr) {
            const int t = t0 + wr*64 + mr*16 + g*4 + rr;
            #pragma unroll
            for (int ct = 0; ct < 4; ++ct) {
                const int r = wc*64 + ct*16 + l15;
                const short v = f2b(acc[mr][ct][rr]);
                if (r < RANK) xqp[(size_t)t*RANK + r] = v;
                else          xkp[(size_t)t*RANK + r - RANK] = v;
            }
        }
}

// ---------------------------------------------------------------------------
// lr_vg8: vT = VOt . xb^T on the R7-verified 4-phase schedule (unchanged).
// ---------------------------------------------------------------------------
__global__ __launch_bounds__(512, 2) void lr_vg8(const short* __restrict__ VOt,
                                                 const short* __restrict__ xb,
                                                 short* __restrict__ vT)
{
    extern __shared__ __align__(16) short lds[];
    short* As = lds;
    short* Bs = lds + 32768;
    const int bid = blockIdx.x;
    const int xcd = bid & 7, jb = bid >> 3;
    const int et = xcd >> 1;
    const int bu = (xcd & 1)*32 + jb;
    const int b = bu >> 4, ut = bu & 15;
    const int e0 = et*256, u0 = ut*256;
    const int tid = threadIdx.x, lane = tid & 63, w = tid >> 6;
    const int wr = w >> 2, wc = w & 3;
    const int l15 = lane & 15, g = lane >> 4;
    const int rx = l15 & 7;

    const short* Ab = VOt + (size_t)e0*DIM;
    const short* Bb = xb + ((size_t)(b*SEQ) + u0)*DIM;

    int aA0[2], aA1[2], aB0[2], aB1[2];
    int dA0[2], dA1[2], dB0[2], dB1[2];
    #pragma unroll
    for (int j = 0; j < 2; ++j) {
        const int s = tid + 512*j;
        const int cl = s >> 6, v = s & 63;
        const int vr = v >> 3, vk = ((v & 7) ^ vr)*8;
        const int cA0 = (cl < 8) ? cl : cl + 8;
        const int cA1 = cA0 + 8;
        const int cB0 = ((cl >> 2) << 3) + (cl & 3);
        const int cB1 = cB0 + 4;
        aA0[j] = (cA0*8 + vr)*DIM + vk;  dA0[j] = cA0*512 + v*8;
        aA1[j] = (cA1*8 + vr)*DIM + vk;  dA1[j] = cA1*512 + v*8;
        aB0[j] = (cB0*8 + vr)*DIM + vk;  dB0[j] = cB0*512 + v*8;
        aB1[j] = (cB1*8 + vr)*DIM + vk;  dB1[j] = cB1*512 + v*8;
    }

    f32x4 acc[8][4] = {};
    short8 af[4][2], bf[4][2];

    #pragma unroll
    for (int j = 0; j < 2; ++j) gld16(Ab + aA0[j], &As[dA0[j]]);
    #pragma unroll
    for (int j = 0; j < 2; ++j) gld16(Bb + aB0[j], &Bs[dB0[j]]);
    #pragma unroll
    for (int j = 0; j < 2; ++j) gld16(Bb + aB1[j], &Bs[dB1[j]]);
    #pragma unroll
    for (int j = 0; j < 2; ++j) gld16(Ab + aA1[j], &As[dA1[j]]);
    asm volatile("s_waitcnt vmcnt(4)" ::: "memory");
    __builtin_amdgcn_s_barrier();
    __builtin_amdgcn_sched_barrier(0);

    for (int kt = 0; kt < 15; ++kt) {
        const int buf  = (kt & 1) ? 16384 : 0;
        const int nbuf = 16384 - buf;
        const int kn = (kt + 1)*64;
        const int arow = buf + (wr*128 + l15)*64;
        const int brow = buf + (wc*64 + l15)*64;
        // phase 0
        #pragma unroll
        for (int mf = 0; mf < 4; ++mf)
            #pragma unroll
            for (int ks = 0; ks < 2; ++ks)
                af[mf][ks] = *reinterpret_cast<const short8*>(
                    &As[arow + mf*1024 + ((ks*4 + g) ^ rx)*8]);
        #pragma unroll
        for (int nf = 0; nf < 2; ++nf)
            #pragma unroll
            for (int ks = 0; ks < 2; ++ks)
                bf[nf][ks] = *reinterpret_cast<const short8*>(
                    &Bs[brow + nf*1024 + ((ks*4 + g) ^ rx)*8]);
        #pragma unroll
        for (int j = 0; j < 2; ++j) gld16(Ab + aA0[j] + kn, &As[nbuf + dA0[j]]);
        __builtin_amdgcn_s_barrier();
        asm volatile("s_waitcnt lgkmcnt(0)" ::: "memory");
        __builtin_amdgcn_sched_barrier(0);
        __builtin_amdgcn_s_setprio(1);
        #pragma unroll
        for (int mf = 0; mf < 4; ++mf)
            #pragma unroll
            for (int nf = 0; nf < 2; ++nf)
                #pragma unroll
                for (int ks = 0; ks < 2; ++ks)
                    acc[mf][nf] = MFMA16(af[mf][ks], bf[nf][ks], acc[mf][nf]);
        __builtin_amdgcn_s_setprio(0);
        asm volatile("s_waitcnt vmcnt(4)" ::: "memory");
        __builtin_amdgcn_s_barrier();
        __builtin_amdgcn_sched_barrier(0);
        // phase 1
        #pragma unroll
        for (int nf = 2; nf < 4; ++nf)
            #pragma unroll
            for (int ks = 0; ks < 2; ++ks)
                bf[nf][ks] = *reinterpret_cast<const short8*>(
                    &Bs[brow + nf*1024 + ((ks*4 + g) ^ rx)*8]);
        #pragma unroll
        for (int j = 0; j < 2; ++j) gld16(Bb + aB0[j] + kn, &Bs[nbuf + dB0[j]]);
        __builtin_amdgcn_s_barrier();
        asm volatile("s_waitcnt lgkmcnt(0)" ::: "memory");
        __builtin_amdgcn_sched_barrier(0);
        __builtin_amdgcn_s_setprio(1);
        #pragma unroll
        for (int mf = 0; mf < 4; ++mf)
            #pragma unroll
            for (int nf = 2; nf < 4; ++nf)
                #pragma unroll
                for (int ks = 0; ks < 2; ++ks)
                    acc[mf][nf] = MFMA16(af[mf][ks], bf[nf][ks], acc[mf][nf]);
        __builtin_amdgcn_s_setprio(0);
        asm volatile("s_waitcnt vmcnt(4)" ::: "memory");
        __builtin_amdgcn_s_barrier();
        __builtin_amdgcn_sched_barrier(0);
        // phase 2
        #pragma unroll
        for (int mf = 0; mf < 4; ++mf)
            #pragma unroll
            for (int ks = 0; ks < 2; ++ks)
                af[mf][ks] = *reinterpret_cast<const short8*>(
                    &As[arow + 4096 + mf*1024 + ((ks*4 + g) ^ rx)*8]);
        #pragma unroll
        for (int j = 0; j < 2; ++j) gld16(Bb + aB1[j] + kn, &Bs[nbuf + dB1[j]]);
        __builtin_amdgcn_s_barrier();
        asm volatile("s_waitcnt lgkmcnt(0)" ::: "memory");
        __builtin_amdgcn_sched_barrier(0);
        __builtin_amdgcn_s_setprio(1);
        #pragma unroll
        for (int mf = 0; mf < 4; ++mf)
            #pragma unroll
            for (int nf = 0; nf < 2; ++nf)
                #pragma unroll
                for (int ks = 0; ks < 2; ++ks)
                    acc[mf+4][nf] = MFMA16(af[mf][ks], bf[nf][ks], acc[mf+4][nf]);
        __builtin_amdgcn_s_setprio(0);
        __builtin_amdgcn_s_barrier();
        __builtin_amdgcn_sched_barrier(0);
        // phase 3
        #pragma unroll
        for (int j = 0; j < 2; ++j) gld16(Ab + aA1[j] + kn, &As[nbuf + dA1[j]]);
        __builtin_amdgcn_s_setprio(1);
        #pragma unroll
        for (int mf = 0; mf < 4; ++mf)
            #pragma unroll
            for (int nf = 2; nf < 4; ++nf)
                #pragma unroll
                for (int ks = 0; ks < 2; ++ks)
                    acc[mf+4][nf] = MFMA16(af[mf][ks], bf[nf][ks], acc[mf+4][nf]);
        __builtin_amdgcn_s_setprio(0);
        asm volatile("s_waitcnt vmcnt(4)" ::: "memory");
        __builtin_amdgcn_s_barrier();
        __builtin_amdgcn_sched_barrier(0);
    }
    asm volatile("s_waitcnt vmcnt(0)" ::: "memory");
    __builtin_amdgcn_s_barrier();
    __builtin_amdgcn_sched_barrier(0);
    {
        const int arow = 16384 + (wr*128 + l15)*64;
        const int brow = 16384 + (wc*64 + l15)*64;
        #pragma unroll
        for (int mf = 0; mf < 4; ++mf)
            #pragma unroll
            for (int ks = 0; ks < 2; ++ks)
                af[mf][ks] = *reinterpret_cast<const short8*>(
                    &As[arow + mf*1024 + ((ks*4 + g) ^ rx)*8]);
        #pragma unroll
        for (int nf = 0; nf < 4; ++nf)
            #pragma unroll
            for (int ks = 0; ks < 2; ++ks)
                bf[nf][ks] = *reinterpret_cast<const short8*>(
                    &Bs[brow + nf*1024 + ((ks*4 + g) ^ rx)*8]);
        #pragma unroll
        for (int mf = 0; mf < 4; ++mf)
            #pragma unroll
            for (int nf = 0; nf < 4; ++nf)
                #pragma unroll
                for (int ks = 0; ks < 2; ++ks)
                    acc[mf][nf] = MFMA16(af[mf][ks], bf[nf][ks], acc[mf][nf]);
        #pragma unroll
        for (int mf = 0; mf < 4; ++mf)
            #pragma unroll
            for (int ks = 0; ks < 2; ++ks)
                af[mf][ks] = *reinterpret_cast<const short8*>(
                    &As[arow + 4096 + mf*1024 + ((ks*4 + g) ^ rx)*8]);
        #pragma unroll
        for (int mf = 0; mf < 4; ++mf)
            #pragma unroll
            for (int nf = 0; nf < 4; ++nf)
                #pragma unroll
                for (int ks = 0; ks < 2; ++ks)
                    acc[mf+4][nf] = MFMA16(af[mf][ks], bf[nf][ks], acc[mf+4][nf]);
    }
    #pragma unroll
    for (int mf = 0; mf < 8; ++mf)
        #pragma unroll
        for (int rr = 0; rr < 4; ++rr) {
            const int e = e0 + wr*128 + mf*16 + g*4 + rr;
            short* orow = vT + ((size_t)(b*DIM) + e)*SEQ + u0 + wc*64;
            #pragma unroll
            for (int nf = 0; nf < 4; ++nf)
                orow[nf*16 + l15] = f2b(acc[mf][nf][rr]);
        }
}

// ---------------------------------------------------------------------------
// lr_vgemm2: fallback (m97 128^2, K=1024) if dynamic-LDS attr fails.
// ---------------------------------------------------------------------------
__global__ __launch_bounds__(256, 4) void lr_vgemm2(const short* __restrict__ VOt,
                                                    const short* __restrict__ xb,
                                                    short* __restrict__ vT)
{
    __shared__ __align__(16) short As[128*64];
    __shared__ __align__(16) short Bs[128*64];
    const int i = blockIdx.x;
    const int etile = i & 7, j = i >> 3;
    const int ut = j & 31, b = j >> 5;
    const int e0 = etile*128, u0 = ut*128;
    const int tid = threadIdx.x, lane = tid & 63, w = tid >> 6;
    const int l15 = lane & 15, g = lane >> 4;
    const int wr = w >> 1, wc = w & 1;
    const short* Ab = VOt + (size_t)e0*DIM;
    const short* Bb = xb + ((size_t)(b*SEQ) + u0)*DIM;
    const int srow = lane >> 3;
    const int skc  = ((lane & 7) ^ srow)*8;
    const int rx = l15 & 7;

    f32x4 acc[4][4] = {};
    #pragma unroll
    for (int jj = 0; jj < 4; ++jj) {
        const int ch = 4*w + jj, row = ch*8 + srow;
        gld16(Ab + (size_t)row*DIM + skc, &As[ch*512]);
        gld16(Bb + (size_t)row*DIM + skc, &Bs[ch*512]);
    }
    for (int kt = 0; kt < 16; ++kt) {
        __syncthreads();
        #pragma unroll
        for (int ks = 0; ks < 2; ++ks) {
            short8 af[4], bfr[4];
            #pragma unroll
            for (int mr = 0; mr < 4; ++mr)
                af[mr] = *reinterpret_cast<const short8*>(
                    &As[(wr*64 + mr*16 + l15)*64 + ((ks*4 + g) ^ rx)*8]);
            #pragma unroll
            for (int ct = 0; ct < 4; ++ct)
                bfr[ct] = *reinterpret_cast<const short8*>(
                    &Bs[(wc*64 + ct*16 + l15)*64 + ((ks*4 + g) ^ rx)*8]);
            #pragma unroll
            for (int mr = 0; mr < 4; ++mr)
                #pragma unroll
                for (int ct = 0; ct < 4; ++ct)
                    acc[mr][ct] = MFMA16(af[mr], bfr[ct], acc[mr][ct]);
        }
        if (kt < 15) {
            __syncthreads();
            const int k0 = (kt + 1)*64;
            #pragma unroll
            for (int jj = 0; jj < 4; ++jj) {
                const int ch = 4*w + jj, row = ch*8 + srow;
                gld16(Ab + (size_t)row*DIM + k0 + skc, &As[ch*512]);
                gld16(Bb + (size_t)row*DIM + k0 + skc, &Bs[ch*512]);
            }
        }
    }
    #pragma unroll
    for (int mr = 0; mr < 4; ++mr)
        #pragma unroll
        for (int rr = 0; rr < 4; ++rr) {
            const int e = e0 + wr*64 + mr*16 + g*4 + rr;
            short* orow = vT + ((size_t)(b*DIM) + e)*SEQ + u0 + wc*64;
            #pragma unroll
            for (int ct = 0; ct < 4; ++ct)
                orow[ct*16 + l15] = f2b(acc[mr][ct][rr]);
        }
}

// ---------------------------------------------------------------------------
// lr_pexp: P_un[gq][u] = exp2(S*cl) bf16 + partial row sums ps[gq][ut].
// ---------------------------------------------------------------------------
__global__ __launch_bounds__(256, 4) void lr_pexp(const short* __restrict__ ws,
                                                  short* __restrict__ P,
                                                  float* __restrict__ ps)
{
    __shared__ __align__(16) short ptile[128*136];
    __shared__ float sred[4][128];
    const int i = blockIdx.x;
    const int qt = i >> 5, ut = i & 31;
    const int b = qt >> 5;
    const int tid = threadIdx.x, lane = tid & 63, w = tid >> 6;
    const int l15 = lane & 15, g = lane >> 4;
    const float cl = 0.045084220f;   // log2(e)/32
    const int q0 = qt*128;

    const short* xqb = ws + XQ_OFF + (size_t)q0*RANK;
    const short* xkb = ws + XK_OFF + ((size_t)(b*SEQ) + ut*128)*RANK;

    f32x4 acc[2][8] = {};
    #pragma unroll
    for (int ks = 0; ks < 2; ++ks) {
        short8 ak[2], bq[8];
        #pragma unroll
        for (int mr = 0; mr < 2; ++mr)
            ak[mr] = *reinterpret_cast<const short8*>(
                xkb + (size_t)(32*w + mr*16 + l15)*RANK + ks*32 + g*8);
        #pragma unroll
        for (int ct = 0; ct < 8; ++ct)
            bq[ct] = *reinterpret_cast<const short8*>(
                xqb + (size_t)(ct*16 + l15)*RANK + ks*32 + g*8);
        #pragma unroll
        for (int mr = 0; mr < 2; ++mr)
            #pragma unroll
            for (int ct = 0; ct < 8; ++ct)
                acc[mr][ct] = MFMA16(ak[mr], bq[ct], acc[mr][ct]);
    }
    float s[8] = {0.f,0.f,0.f,0.f,0.f,0.f,0.f,0.f};
    #pragma unroll
    for (int mr = 0; mr < 2; ++mr)
        #pragma unroll
        for (int ct = 0; ct < 8; ++ct) {
            short4v pk;
            #pragma unroll
            for (int r = 0; r < 4; ++r) {
                const short pb = f2b(__builtin_amdgcn_exp2f(acc[mr][ct][r]*cl));
                pk[r] = pb;
                s[ct] += b2f(pb);
            }
            *reinterpret_cast<short4v*>(
                &ptile[(ct*16 + l15)*136 + 32*w + mr*16 + g*4]) = pk;
        }
    #pragma unroll
    for (int ct = 0; ct < 8; ++ct) {
        s[ct] += __shfl_xor(s[ct], 16);
        s[ct] += __shfl_xor(s[ct], 32);
    }
    if (g == 0) {
        #pragma unroll
        for (int ct = 0; ct < 8; ++ct) sred[w][ct*16 + l15] = s[ct];
    }
    __syncthreads();
    #pragma unroll
    for (int j = 0; j < 8; ++j) {
        const int id = tid + 256*j;
        const int row = id >> 4, seg = id & 15;
        const uint4 v = *reinterpret_cast<const uint4*>(&ptile[row*136 + seg*8]);
        *reinterpret_cast<uint4*>(
            P + (size_t)(q0 + row)*SEQ + ut*128 + seg*8) = v;
    }
    if (tid < 128)
        ps[(size_t)(q0 + tid)*32 + ut] =
            sred[0][tid] + sred[1][tid] + sred[2][tid] + sred[3][tid];
}

// ---------------------------------------------------------------------------
// lr_psum (fallback path only): linv[gq] = 1 / sum_ut ps[gq][ut].
// ---------------------------------------------------------------------------
__global__ __launch_bounds__(256) void lr_psum(const float* __restrict__ ps,
                                               float* __restrict__ linv)
{
    const int gq = blockIdx.x*256 + threadIdx.x;
    const float* p = ps + (size_t)gq*32;
    float s = 0.f;
    #pragma unroll
    for (int j = 0; j < 32; ++j) s += p[j];
    linv[gq] = 1.0f / s;
}

// ---------------------------------------------------------------------------
// lr_pv8: 256x256x64 GEMM, DEEP pipeline (m201-style, region-reuse).
// Regions per buffer: A0={ch 0-7,16-23}, A1={8-15,24-31}, B0={0-3,8-11,
// 16-19,24-27}, B1=B0+4. Tile kt reads buf=kt&1: ph0 A0+B0, ph1 B1, ph2 A1.
// Staging (2 tiles deep, into just-freed regions):
//   ph0(kt): A1(kt+1)->nbuf.A1   [freed end-ph2(kt-1); guard 1<=kt<63]
//   ph1(kt): A0(kt+2)->buf.A0    [freed end-ph0(kt); guard kt<62]
//   ph2(kt): B0(kt+2)->buf.B0    [freed end-ph0(kt); guard kt<62]
//   ph3(kt): B1(kt+2)->buf.B1    [freed end-ph1(kt); guard kt<62]
// One wait/tile: end-ph3 vmcnt(6) (newest needed load = A1(kt+1) at ph0(kt),
// 6 loads older than the wait). kt==62: vmcnt(0) drains the tail.
// Prologue stages tiles 0+1 fully, one-time vmcnt(0).
// linv computed in-block from ps (ledger cleaned with vmcnt(0) first).
// ---------------------------------------------------------------------------
__global__ __launch_bounds__(512, 2) void lr_pv8(const short* __restrict__ P,
                                                 const short* __restrict__ vT,
                                                 const float* __restrict__ ps,
                                                 float* __restrict__ out)
{
    extern __shared__ __align__(16) short lds[];
    __shared__ float linv_lds[256];
    short* As = lds;
    short* Bs = lds + 32768;
    const int bid = blockIdx.x;
    const int qt = (bid & 7)*8 + (bid >> 5);
    const int nt = (bid >> 3) & 3;
    const int q0 = qt*256, d0 = nt*256, b = qt >> 4;
    const int tid = threadIdx.x, lane = tid & 63, w = tid >> 6;
    const int wr = w >> 2, wc = w & 3;
    const int l15 = lane & 15, g = lane >> 4;
    const int rx = l15 & 7;

    if (tid < 256) {
        const float* pp = ps + (size_t)(q0 + tid)*32;
        float s = 0.f;
        #pragma unroll
        for (int jj = 0; jj < 32; ++jj) s += pp[jj];
        linv_lds[tid] = 1.0f / s;
    }
    asm volatile("s_waitcnt vmcnt(0)" ::: "memory");   // clean vmcnt ledger
    __builtin_amdgcn_sched_barrier(0);

    const short* Ab = P + (size_t)q0*SEQ;
    const short* Bb = vT + ((size_t)(b*DIM) + d0)*SEQ;

    int aA0[2], aA1[2], aB0[2], aB1[2];
    int dA0[2], dA1[2], dB0[2], dB1[2];
    #pragma unroll
    for (int j = 0; j < 2; ++j) {
        const int s = tid + 512*j;
        const int cl = s >> 6, v = s & 63;
        const int vr = v >> 3, vk = ((v & 7) ^ vr)*8;
        const int cA0 = (cl < 8) ? cl : cl + 8;
        const int cA1 = cA0 + 8;
        const int cB0 = ((cl >> 2) << 3) + (cl & 3);
        const int cB1 = cB0 + 4;
        aA0[j] = (cA0*8 + vr)*SEQ + vk;  dA0[j] = cA0*512 + v*8;
        aA1[j] = (cA1*8 + vr)*SEQ + vk;  dA1[j] = cA1*512 + v*8;
        aB0[j] = (cB0*8 + vr)*SEQ + vk;  dB0[j] = cB0*512 + v*8;
        aB1[j] = (cB1*8 + vr)*SEQ + vk;  dB1[j] = cB1*512 + v*8;
    }

    f32x4 acc[8][4] = {};
    short8 af[4][2], bf[4][2];

    // prologue: stage tiles 0 (buf 0) and 1 (buf 16384) fully; full drain once
    #pragma unroll
    for (int t = 0; t < 2; ++t) {
        const int bo = t ? 16384 : 0, ko = t*64;
        #pragma unroll
        for (int j = 0; j < 2; ++j) gld16(Ab + aA0[j] + ko, &As[bo + dA0[j]]);
        #pragma unroll
        for (int j = 0; j < 2; ++j) gld16(Bb + aB0[j] + ko, &Bs[bo + dB0[j]]);
        #pragma unroll
        for (int j = 0; j < 2; ++j) gld16(Bb + aB1[j] + ko, &Bs[bo + dB1[j]]);
        #pragma unroll
        for (int j = 0; j < 2; ++j) gld16(Ab + aA1[j] + ko, &As[bo + dA1[j]]);
    }
    asm volatile("s_waitcnt vmcnt(0)" ::: "memory");
    __builtin_amdgcn_s_barrier();
    __builtin_amdgcn_sched_barrier(0);

    for (int kt = 0; kt < 64; ++kt) {
        const int buf  = (kt & 1) ? 16384 : 0;
        const int nbuf = 16384 - buf;
        const int k1 = (kt + 1)*64, k2 = (kt + 2)*64;
        const int arow = buf + (wr*128 + l15)*64;
        const int brow = buf + (wc*64 + l15)*64;
        const bool st1 = (kt >= 1) && (kt < 63);
        const bool st2 = kt < 62;
        // ---- phase 0: read A0(m0-3)+B0(n0-1); stage A1(kt+1)->nbuf ----
        #pragma unroll
        for (int mf = 0; mf < 4; ++mf)
            #pragma unroll
            for (int ks = 0; ks < 2; ++ks)
                af[mf][ks] = *reinterpret_cast<const short8*>(
                    &As[arow + mf*1024 + ((ks*4 + g) ^ rx)*8]);
        #pragma unroll
        for (int nf = 0; nf < 2; ++nf)
            #pragma unroll
            for (int ks = 0; ks < 2; ++ks)
                bf[nf][ks] = *reinterpret_cast<const short8*>(
                    &Bs[brow + nf*1024 + ((ks*4 + g) ^ rx)*8]);
        if (st1) {
            #pragma unroll
            for (int j = 0; j < 2; ++j)
                gld16(Ab + aA1[j] + k1, &As[nbuf + dA1[j]]);
        }
        __builtin_amdgcn_s_barrier();
        asm volatile("s_waitcnt lgkmcnt(0)" ::: "memory");
        __builtin_amdgcn_sched_barrier(0);
        __builtin_amdgcn_s_setprio(1);
        #pragma unroll
        for (int mf = 0; mf < 4; ++mf)
            #pragma unroll
            for (int nf = 0; nf < 2; ++nf)
                #pragma unroll
                for (int ks = 0; ks < 2; ++ks)
                    acc[mf][nf] = MFMA16(af[mf][ks], bf[nf][ks], acc[mf][nf]);
        __builtin_amdgcn_s_setprio(0);
        __builtin_amdgcn_s_barrier();
        __builtin_amdgcn_sched_barrier(0);
        // ---- phase 1: read B1(n2-3); stage A0(kt+2)->buf.A0 (freed ph0) ----
        #pragma unroll
        for (int nf = 2; nf < 4; ++nf)
            #pragma unroll
            for (int ks = 0; ks < 2; ++ks)
                bf[nf][ks] = *reinterpret_cast<const short8*>(
                    &Bs[brow + nf*1024 + ((ks*4 + g) ^ rx)*8]);
        if (st2) {
            #pragma unroll
            for (int j = 0; j < 2; ++j)
                gld16(Ab + aA0[j] + k2, &As[buf + dA0[j]]);
        }
        __builtin_amdgcn_s_barrier();
        asm volatile("s_waitcnt lgkmcnt(0)" ::: "memory");
        __builtin_amdgcn_sched_barrier(0);
        __builtin_amdgcn_s_setprio(1);
        #pragma unroll
        for (int mf = 0; mf < 4; ++mf)
            #pragma unroll
            for (int nf = 2; nf < 4; ++nf)
                #pragma unroll
                for (int ks = 0; ks < 2; ++ks)
                    acc[mf][nf] = MFMA16(af[mf][ks], bf[nf][ks], acc[mf][nf]);
        __builtin_amdgcn_s_setprio(0);
        __builtin_amdgcn_s_barrier();
        __builtin_amdgcn_sched_barrier(0);
        // ---- phase 2: read A1(m4-7); stage B0(kt+2)->buf.B0 (freed ph0) ----
        #pragma unroll
        for (int mf = 0; mf < 4; ++mf)
            #pragma unroll
            for (int ks = 0; ks < 2; ++ks)
                af[mf][ks] = *reinterpret_cast<const short8*>(
                    &As[arow + 4096 + mf*1024 + ((ks*4 + g) ^ rx)*8]);
        if (st2) {
            #pragma unroll
            for (int j = 0; j < 2; ++j)
                gld16(Bb + aB0[j] + k2, &Bs[buf + dB0[j]]);
        }
        __builtin_amdgcn_s_barrier();
        asm volatile("s_waitcnt lgkmcnt(0)" ::: "memory");
        __builtin_amdgcn_sched_barrier(0);
        __builtin_amdgcn_s_setprio(1);
        #pragma unroll
        for (int mf = 0; mf < 4; ++mf)
            #pragma unroll
            for (int nf = 0; nf < 2; ++nf)
                #pragma unroll
                for (int ks = 0; ks < 2; ++ks)
                    acc[mf+4][nf] = MFMA16(af[mf][ks], bf[nf][ks], acc[mf+4][nf]);
        __builtin_amdgcn_s_setprio(0);
        __builtin_amdgcn_s_barrier();
        __builtin_amdgcn_sched_barrier(0);
        // ---- phase 3: stage B1(kt+2)->buf.B1 (freed ph1); MFMA regs-only ----
        if (st2) {
            #pragma unroll
            for (int j = 0; j < 2; ++j)
                gld16(Bb + aB1[j] + k2, &Bs[buf + dB1[j]]);
        }
        __builtin_amdgcn_s_setprio(1);
        #pragma unroll
        for (int mf = 0; mf < 4; ++mf)
            #pragma unroll
            for (int nf = 2; nf < 4; ++nf)
                #pragma unroll
                for (int ks = 0; ks < 2; ++ks)
                    acc[mf+4][nf] = MFMA16(af[mf][ks], bf[nf][ks], acc[mf+4][nf]);
        __builtin_amdgcn_s_setprio(0);
        if (kt < 62) {
            asm volatile("s_waitcnt vmcnt(6)" ::: "memory");
        } else if (kt == 62) {
            asm volatile("s_waitcnt vmcnt(0)" ::: "memory");
        }
        __builtin_amdgcn_s_barrier();
        __builtin_amdgcn_sched_barrier(0);
    }
    #pragma unroll
    for (int mf = 0; mf < 8; ++mf)
        #pragma unroll
        for (int rr = 0; rr < 4; ++rr) {
            const int ql = wr*128 + mf*16 + g*4 + rr;
            const float sc = linv_lds[ql];
            float* rp = out + (size_t)(q0 + ql)*DIM + d0 + wc*64;
            #pragma unroll
            for (int nf = 0; nf < 4; ++nf)
                rp[nf*16 + l15] = acc[mf][nf][rr]*sc;
        }
}

// ---------------------------------------------------------------------------
// lr_pv: R5 2-phase 128^2 GEMM -- fallback if 128KB dynamic LDS unavailable.
// ---------------------------------------------------------------------------
__global__ __launch_bounds__(256, 4) void lr_pv(const short* __restrict__ P,
                                                const short* __restrict__ vT,
                                                const float* __restrict__ linv,
                                                float* __restrict__ out)
{
    __shared__ __align__(16) short As[128*64];
    __shared__ __align__(16) short Bs[128*64];
    const int i = blockIdx.x;
    const int qlo = i & 7, j = i >> 3;
    const int nt = j & 7, qhi = j >> 3;
    const int qt = qhi*8 + qlo;
    const int q0 = qt*128, d0 = nt*128, b = qt >> 5;
    const int tid = threadIdx.x, lane = tid & 63, w = tid >> 6;
    const int l15 = lane & 15, g = lane >> 4;
    const int wr = w >> 1, wc = w & 1;

    const short* Ab = P + (size_t)q0*SEQ;
    const short* Bb = vT + ((size_t)(b*DIM) + d0)*SEQ;
    const int srow = lane >> 3;
    const int skc  = ((lane & 7) ^ srow)*8;
    const int rx = l15 & 7;

    f32x4 acc[4][4] = {};
    #pragma unroll
    for (int jj = 0; jj < 4; ++jj) {
        const int ch = 4*w + jj, row = ch*8 + srow;
        gld16(Ab + (size_t)row*SEQ + skc, &As[ch*512]);
        gld16(Bb + (size_t)row*SEQ + skc, &Bs[ch*512]);
    }
    for (int kt = 0; kt < 64; ++kt) {
        __syncthreads();
        #pragma unroll
        for (int ks = 0; ks < 2; ++ks) {
            short8 af[4], bfr[4];
            #pragma unroll
            for (int mr = 0; mr < 4; ++mr)
                af[mr] = *reinterpret_cast<const short8*>(
                    &As[(wr*64 + mr*16 + l15)*64 + ((ks*4 + g) ^ rx)*8]);
            #pragma unroll
            for (int ct = 0; ct < 4; ++ct)
                bfr[ct] = *reinterpret_cast<const short8*>(
                    &Bs[(wc*64 + ct*16 + l15)*64 + ((ks*4 + g) ^ rx)*8]);
            #pragma unroll
            for (int mr = 0; mr < 4; ++mr)
                #pragma unroll
                for (int ct = 0; ct < 4; ++ct)
                    acc[mr][ct] = MFMA16(af[mr], bfr[ct], acc[mr][ct]);
        }
        if (kt < 63) {
            __syncthreads();
            const int k0 = (kt + 1)*64;
            #pragma unroll
            for (int jj = 0; jj < 4; ++jj) {
                const int ch = 4*w + jj, row = ch*8 + srow;
                gld16(Ab + (size_t)row*SEQ + k0 + skc, &As[ch*512]);
                gld16(Bb + (size_t)row*SEQ + k0 + skc, &Bs[ch*512]);
            }
        }
    }
    #pragma unroll
    for (int mr = 0; mr < 4; ++mr)
        #pragma unroll
        for (int rr = 0; rr < 4; ++rr) {
            const int q = q0 + wr*64 + mr*16 + g*4 + rr;
            const float sc = linv[q];
            float* rp = out + (size_t)q*DIM + d0 + wc*64;
            #pragma unroll
            for (int ct = 0; ct < 4; ++ct)
                rp[ct*16 + l15] = acc[mr][ct][rr]*sc;
        }
}

// ===========================================================================
// Fallback path (used only if ws_size too small): R3 kernels, unchanged.
// ===========================================================================
__global__ __launch_bounds__(256) void lr_proj(const float* __restrict__ x,
                                               const float* __restrict__ Qw,
                                               const float* __restrict__ Kw,
                                               short* __restrict__ ws)
{
    __shared__ __align__(16) short ldsB[64*40];
    const int i = blockIdx.x;
    const int ttile = i & 63, b = i >> 6;
    const int tid = threadIdx.x, lane = tid & 63, w = tid >> 6;
    const int l15 = lane & 15, g = lane >> 4;
    const int t0 = ttile * 64;

    f32x4 acc[2][4] = {};
    for (int e0 = 0; e0 < DIM; e0 += 32) {
        const int tr = tid >> 2, seg = tid & 3;
        const float* px = x + (size_t)(b*SEQ + t0 + tr)*DIM + e0 + seg*8;
        const float4 f0 = *reinterpret_cast<const float4*>(px);
        const float4 f1 = *reinterpret_cast<const float4*>(px + 4);
        __syncthreads();
        {
            short* d = &ldsB[tr*40 + seg*8];
            d[0]=f2b(f0.x); d[1]=f2b(f0.y); d[2]=f2b(f0.z); d[3]=f2b(f0.w);
            d[4]=f2b(f1.x); d[5]=f2b(f1.y); d[6]=f2b(f1.z); d[7]=f2b(f1.w);
        }
        __syncthreads();
        #pragma unroll
        for (int mr = 0; mr < 2; ++mr) {
            const int r = 32*w + mr*16 + l15;
            const float* wp = (r < RANK ? Qw + (size_t)r*DIM
                                        : Kw + (size_t)(r - RANK)*DIM) + e0 + g*8;
            const short8 a = cvt8(wp);
            #pragma unroll
            for (int ct = 0; ct < 4; ++ct) {
                const short8 bb = *reinterpret_cast<const short8*>(
                    &ldsB[(ct*16 + l15)*40 + g*8]);
                acc[mr][ct] = MFMA16(a, bb, acc[mr][ct]);
            }
        }
    }
    short* xqp = ws + XQ_OFF;
    short* xkp = ws + XK_OFF;
    #pragma unroll
    for (int mr = 0; mr < 2; ++mr) {
        const int rb = 32*w + mr*16 + g*4;
        short* base = (rb < RANK) ? (xqp + rb) : (xkp + (rb - RANK));
        #pragma unroll
        for (int ct = 0; ct < 4; ++ct) {
            const int t = t0 + ct*16 + l15;
            short4v pk;
            pk[0]=f2b(acc[mr][ct][0]); pk[1]=f2b(acc[mr][ct][1]);
            pk[2]=f2b(acc[mr][ct][2]); pk[3]=f2b(acc[mr][ct][3]);
            *reinterpret_cast<short4v*>(base + (size_t)(b*SEQ + t)*RANK) = pk;
        }
    }
}

__global__ __launch_bounds__(256) void lr_vgemm(const float* __restrict__ x,
                                                const float* __restrict__ VO,
                                                short* __restrict__ ws)
{
    short* vT = ws + VT_OFF;
    __shared__ __align__(16) short ldsA[128*40];
    __shared__ __align__(16) short ldsB[128*40];
    const int i = blockIdx.x;
    const int dtile = i & 7, utile = (i >> 3) & 31, b = i >> 8;
    const int d0 = dtile*128, u0 = utile*128;
    const int tid = threadIdx.x, lane = tid & 63, w = tid >> 6;
    const int l15 = lane & 15, g = lane >> 4;
    const int wr = w >> 1, wc = w & 1;

    f32x4 acc[4][4] = {};
    for (int e0 = 0; e0 < DIM; e0 += 32) {
        const int dcol = tid & 127, erg = (tid >> 7)*16;
        float va[16];
        #pragma unroll
        for (int j = 0; j < 16; ++j)
            va[j] = VO[(size_t)(e0 + erg + j)*DIM + d0 + dcol];
        const int ur = tid >> 1, esg = (tid & 1)*16;
        const float* pb = x + (size_t)(b*SEQ + u0 + ur)*DIM + e0 + esg;
        float4 vb0 = reinterpret_cast<const float4*>(pb)[0];
        float4 vb1 = reinterpret_cast<const float4*>(pb)[1];
        float4 vb2 = reinterpret_cast<const float4*>(pb)[2];
        float4 vb3 = reinterpret_cast<const float4*>(pb)[3];
        __syncthreads();
        #pragma unroll
        for (int j = 0; j < 16; ++j) ldsA[dcol*40 + erg + j] = f2b(va[j]);
        {
            short* d = &ldsB[ur*40 + esg];
            d[0]=f2b(vb0.x); d[1]=f2b(vb0.y); d[2]=f2b(vb0.z); d[3]=f2b(vb0.w);
            d[4]=f2b(vb1.x); d[5]=f2b(vb1.y); d[6]=f2b(vb1.z); d[7]=f2b(vb1.w);
            d[8]=f2b(vb2.x); d[9]=f2b(vb2.y); d[10]=f2b(vb2.z); d[11]=f2b(vb2.w);
            d[12]=f2b(vb3.x); d[13]=f2b(vb3.y); d[14]=f2b(vb3.z); d[15]=f2b(vb3.w);
        }
        __syncthreads();
        short8 af[4], bfr[4];
        #pragma unroll
        for (int mr = 0; mr < 4; ++mr)
            af[mr] = *reinterpret_cast<const short8*>(
                &ldsA[(wr*64 + mr*16 + l15)*40 + g*8]);
        #pragma unroll
        for (int ct = 0; ct < 4; ++ct)
            bfr[ct] = *reinterpret_cast<const short8*>(
                &ldsB[(wc*64 + ct*16 + l15)*40 + g*8]);
        #pragma unroll
        for (int mr = 0; mr < 4; ++mr)
            #pragma unroll
            for (int ct = 0; ct < 4; ++ct)
                acc[mr][ct] = MFMA16(af[mr], bfr[ct], acc[mr][ct]);
    }
    #pragma unroll
    for (int mr = 0; mr < 4; ++mr)
        #pragma unroll
        for (int rr = 0; rr < 4; ++rr) {
            const int d = d0 + wr*64 + mr*16 + g*4 + rr;
            short* orow = vT + (size_t)(b*DIM + d)*SEQ + u0 + wc*64;
            #pragma unroll
            for (int ct = 0; ct < 4; ++ct)
                orow[ct*16 + l15] = f2b(acc[mr][ct][rr]);
        }
}

__global__ __launch_bounds__(256) void lr_stats(const short* __restrict__ ws,
                                                float* __restrict__ pm,
                                                float* __restrict__ pl)
{
    const short* xq = ws + XQ_OFF;
    const short* xk = ws + XK_OFF;
    const int i = blockIdx.x;
    const int us = i & 3, qtile = (i >> 2) & 63, b = i >> 8;
    const int tid = threadIdx.x, lane = tid & 63, w = tid >> 6;
    const int l15 = lane & 15, g = lane >> 4;
    const float cl = 0.045084220f;

    short8 qb0, qb1;
    {
        const short* p = xq + (size_t)(b*SEQ + qtile*64 + 16*w + l15)*RANK + g*8;
        qb0 = *reinterpret_cast<const short8*>(p);
        qb1 = *reinterpret_cast<const short8*>(p + 32);
    }
    const short* kb = xk + (size_t)b*SEQ*RANK;

    float m = -3.0e38f, l = 0.f;
    for (int it = 0; it < 16; ++it) {
        const int ub = us*1024 + it*64;
        f32x4 S[4];
        #pragma unroll
        for (int t = 0; t < 4; ++t) {
            const short* kp = kb + (size_t)(ub + 16*t + l15)*RANK + g*8;
            const short8 a0 = *reinterpret_cast<const short8*>(kp);
            const short8 a1 = *reinterpret_cast<const short8*>(kp + 32);
            f32x4 z = {};
            z = MFMA16(a0, qb0, z);
            z = MFMA16(a1, qb1, z);
            S[t] = z;
        }
        float mt = S[0][0];
        #pragma unroll
        for (int t = 0; t < 4; ++t)
            #pragma unroll
            for (int r = 0; r < 4; ++r) mt = fmaxf(mt, S[t][r]);
        const float mn = fmaxf(m, mt);
        l *= __builtin_amdgcn_exp2f((m - mn)*cl);
        const float mc = mn*cl;
        #pragma unroll
        for (int t = 0; t < 4; ++t)
            #pragma unroll
            for (int r = 0; r < 4; ++r)
                l += __builtin_amdgcn_exp2f(__builtin_fmaf(S[t][r], cl, -mc));
        m = mn;
    }
    #pragma unroll
    for (int mask = 16; mask <= 32; mask <<= 1) {
        const float mo = __shfl_xor(m, mask), lo = __shfl_xor(l, mask);
        const float mn = fmaxf(m, mo);
        l = l*__builtin_amdgcn_exp2f((m - mn)*cl)
          + lo*__builtin_amdgcn_exp2f((mo - mn)*cl);
        m = mn;
    }
    if (g == 0) {
        const int idx = (b*SEQ + qtile*64 + 16*w + l15)*4 + us;
        pm[idx] = m; pl[idx] = l;
    }
}

__global__ __launch_bounds__(256, 4) void lr_flash(const short* __restrict__ ws,
                                                   const float* __restrict__ pm,
                                                   const float* __restrict__ pl,
                                                   float* __restrict__ out)
{
    const short* xq = ws + XQ_OFF;
    const short* xk = ws + XK_OFF;
    const short* vT = ws + VT_OFF;
    __shared__ __align__(16) short vlds[128*64];
    __shared__ __align__(16) short plds[32*64];
    const int i = blockIdx.x;
    const int xcd = i & 7, slot = i >> 3;
    const int combo = xcd + 8*(slot >> 6);
    const int qtile = slot & 63;
    const int b = combo >> 2, dch = combo & 3;
    const int tid = threadIdx.x, lane = tid & 63, w = tid >> 6;
    const int l15 = lane & 15, g = lane >> 4;
    const float cl = 0.045084220f;

    float mC;
    {
        const int base = (b*SEQ + qtile*64 + 16*w + l15)*4;
        const float m0 = pm[base+0], m1 = pm[base+1];
        const float m2 = pm[base+2], m3 = pm[base+3];
        const float mm = fmaxf(fmaxf(m0, m1), fmaxf(m2, m3));
        const float l = pl[base+0]*__builtin_amdgcn_exp2f((m0-mm)*cl)
                      + pl[base+1]*__builtin_amdgcn_exp2f((m1-mm)*cl)
                      + pl[base+2]*__builtin_amdgcn_exp2f((m2-mm)*cl)
                      + pl[base+3]*__builtin_amdgcn_exp2f((m3-mm)*cl);
        mC = -(mm*cl + __builtin_amdgcn_logf(l));
    }
    short8 qb0, qb1;
    {
        const short* p = xq + (size_t)(b*SEQ + qtile*64 + 16*w + l15)*RANK + g*8;
        qb0 = *reinterpret_cast<const short8*>(p);
        qb1 = *reinterpret_cast<const short8*>(p + 32);
    }
    const short* vbase = vT + ((size_t)b*DIM + dch*256)*SEQ;
    const short* kr = xk + (size_t)b*SEQ*RANK + l15*RANK + g*8;
    const int r7 = l15 >> 1;
    const int st_dst = (tid >> 3)*64 + (((tid & 7) ^ ((tid >> 3) & 7))*8);
    const int st_src = (tid >> 2)*SEQ + (tid & 3)*8;
    const int a_base = r7*64 + ((((l15 & 1)*4 + g) ^ r7)*8);
    const int b_base = (32*w + r7)*64 + ((((l15 & 1)*4 + g) ^ r7)*8);
    const int chv = (l15 & 1)*4 + (g >> 1);
    const int pw0 = (8*w + r7)*64 + ((chv ^ r7)*8)       + (g & 1)*4;
    const int pw1 = (8*w + r7)*64 + (((chv + 2) ^ r7)*8) + (g & 1)*4;

    uint4 sreg[4];
    #pragma unroll
    for (int c = 0; c < 4; ++c)
        sreg[c] = *reinterpret_cast<const uint4*>(vbase + st_src + (size_t)c*64*SEQ);
    #pragma unroll
    for (int c = 0; c < 4; ++c)
        *reinterpret_cast<uint4*>(&vlds[st_dst + 2048*c]) = sreg[c];

    f32x4 O[16] = {};
    for (int ub = 0; ub < SEQ; ub += 32) {
        const bool more = (ub + 32 < SEQ);
        if (more) {
            #pragma unroll
            for (int c = 0; c < 4; ++c)
                sreg[c] = *reinterpret_cast<const uint4*>(
                    vbase + st_src + ub + 32 + (size_t)c*64*SEQ);
        }
        #pragma unroll
        for (int t = 0; t < 2; ++t) {
            const short* kp = kr + (size_t)(ub + 16*t)*RANK;
            const short8 a0 = *reinterpret_cast<const short8*>(kp);
            const short8 a1 = *reinterpret_cast<const short8*>(kp + 32);
            f32x4 z = {};
            z = MFMA16(a0, qb0, z);
            z = MFMA16(a1, qb1, z);
            short4v pk;
            #pragma unroll
            for (int r = 0; r < 4; ++r)
                pk[r] = f2b(__builtin_amdgcn_exp2f(__builtin_fmaf(z[r], cl, mC)));
            *reinterpret_cast<short4v*>(&plds[t ? pw1 : pw0]) = pk;
        }
        __syncthreads();
        short8 pa[4];
        #pragma unroll
        for (int qt = 0; qt < 4; ++qt)
            pa[qt] = *reinterpret_cast<const short8*>(&plds[a_base + qt*512]);
        #pragma unroll
        for (int dt = 0; dt < 4; ++dt) {
            const short8 vf = *reinterpret_cast<const short8*>(&vlds[b_base + dt*512]);
            #pragma unroll
            for (int qt = 0; qt < 4; ++qt)
                O[qt*4 + dt] = MFMA16(pa[qt], vf, O[qt*4 + dt]);
        }
        __syncthreads();
        if (more) {
            #pragma unroll
            for (int c = 0; c < 4; ++c)
                *reinterpret_cast<uint4*>(&vlds[st_dst + 2048*c]) = sreg[c];
        }
    }
    #pragma unroll
    for (int qt = 0; qt < 4; ++qt)
        #pragma unroll
        for (int rr = 0; rr < 4; ++rr) {
            const int q = qtile*64 + qt*16 + g*4 + rr;
            float* rowp = out + (size_t)(b*SEQ + q)*DIM + dch*256 + 64*w;
            #pragma unroll
            for (int dt = 0; dt < 4; ++dt)
                rowp[dt*16 + l15] = O[qt*4 + dt][rr];
        }
}

extern "C" void kernel_launch(void* const* d_in, const int* in_sizes, int n_in,
                              void* d_out, int out_size, void* d_ws, size_t ws_size,
                              hipStream_t stream) {
    const float* x  = (const float*)d_in[0];
    const float* Q  = (const float*)d_in[1];
    const float* K  = (const float*)d_in[2];
    const float* VO = (const float*)d_in[3];
    float* out = (float*)d_out;
    short* ws = (short*)d_ws;

    const size_t need = (P_OFF + P_LEN)*2 + (size_t)(BATCH*SEQ)*(32 + 1)*4;
    if (ws_size >= need) {
        short* Pb  = ws + P_OFF;
        short* xb  = Pb;                                   // aliases P (early)
        short* VOt = Pb + (size_t)BATCH*SEQ*DIM;
        short* Wb  = VOt + (size_t)DIM*DIM;
        float* ps  = (float*)(ws + P_OFF + P_LEN);
        float* linv = ps + (size_t)BATCH*SEQ*32;
        const hipError_t e1 = hipFuncSetAttribute(
            reinterpret_cast<const void*>(lr_pv8),
            hipFuncAttributeMaxDynamicSharedMemorySize, 131072);
        const hipError_t e2 = hipFuncSetAttribute(
            reinterpret_cast<const void*>(lr_vg8),
            hipFuncAttributeMaxDynamicSharedMemorySize, 131072);
        lr_cvt   <<<dim3(8512), dim3(256), 0, stream>>>(x, VO, Q, K, xb, VOt, Wb);
        lr_proj2 <<<dim3(128),  dim3(256), 0, stream>>>(xb, Wb, ws);
        if (e2 == hipSuccess)
            lr_vg8   <<<dim3(256), dim3(512), 131072, stream>>>(VOt, xb, ws + VT_OFF);
        else
            lr_vgemm2<<<dim3(1024), dim3(256), 0, stream>>>(VOt, xb, ws + VT_OFF);
        lr_pexp  <<<dim3(4096), dim3(256), 0, stream>>>(ws, Pb, ps);
        if (e1 == hipSuccess) {
            lr_pv8<<<dim3(256), dim3(512), 131072, stream>>>(Pb, ws + VT_OFF, ps, out);
        } else {
            lr_psum<<<dim3(64), dim3(256), 0, stream>>>(ps, linv);
            lr_pv  <<<dim3(1024), dim3(256), 0, stream>>>(Pb, ws + VT_OFF, linv, out);
        }
    } else {
        float* pm = (float*)(ws + VT_END);
        float* pl = pm + BATCH*SEQ*4;
        lr_proj <<<dim3(256),  dim3(256), 0, stream>>>(x, Q, K, ws);
        lr_stats<<<dim3(1024), dim3(256), 0, stream>>>(ws, pm, pl);
        lr_vgemm<<<dim3(1024), dim3(256), 0, stream>>>(x, VO, ws);
        lr_flash<<<dim3(1024), dim3(256), 0, stream>>>(ws, pm, pl, out);
    }
}

// Round 10
// 235.869 us; speedup vs baseline: 1.0331x; 1.0331x over previous
//
#include <hip/hip_runtime.h>
#include <hip/hip_bf16.h>

#define BATCH 4
#define SEQ   4096
#define DIM   1024
#define RANK  64

typedef __attribute__((ext_vector_type(8))) short short8;
typedef __attribute__((ext_vector_type(4))) short short4v;
typedef __attribute__((ext_vector_type(4))) float f32x4;

#define MFMA16(a,b,c) __builtin_amdgcn_mfma_f32_16x16x32_bf16((a),(b),(c),0,0,0)

// workspace layout (in shorts/bf16 elements)
#define XQ_OFF 0
#define XK_OFF (BATCH*SEQ*RANK)
#define VT_OFF (2*BATCH*SEQ*RANK)
#define VT_END (VT_OFF + BATCH*DIM*SEQ)          // 18,874,368 shorts
#define P_OFF  ((size_t)VT_END)
#define P_LEN  ((size_t)BATCH*SEQ*SEQ)           // 67,108,864 shorts (128MB)

__device__ __forceinline__ short f2b(float f) {
    __hip_bfloat16 h = __float2bfloat16(f);
    short s; __builtin_memcpy(&s, &h, sizeof(short));
    return s;
}
__device__ __forceinline__ float b2f(short s) {
    __hip_bfloat16 h; __builtin_memcpy(&h, &s, sizeof(short));
    return __bfloat162float(h);
}
__device__ __forceinline__ short8 cvt8(const float* __restrict__ p) {
    const float4 f0 = *reinterpret_cast<const float4*>(p);
    const float4 f1 = *reinterpret_cast<const float4*>(p + 4);
    short8 r;
    r[0]=f2b(f0.x); r[1]=f2b(f0.y); r[2]=f2b(f0.z); r[3]=f2b(f0.w);
    r[4]=f2b(f1.x); r[5]=f2b(f1.y); r[6]=f2b(f1.z); r[7]=f2b(f1.w);
    return r;
}
__device__ __forceinline__ void gld16(const short* g, short* l) {
    __builtin_amdgcn_global_load_lds(
        (const __attribute__((address_space(1))) void*)g,
        (__attribute__((address_space(3))) void*)l, 16, 0, 0);
}

// ---------------------------------------------------------------------------
// lr_cvt: xb = bf16(x); VOt = bf16(VO^T); Wb = bf16(concat(Q,K)).
// ---------------------------------------------------------------------------
__global__ __launch_bounds__(256) void lr_cvt(const float* __restrict__ x,
                                              const float* __restrict__ VO,
                                              const float* __restrict__ Qw,
                                              const float* __restrict__ Kw,
                                              short* __restrict__ xb,
                                              short* __restrict__ VOt,
                                              short* __restrict__ Wb)
{
    const int bid = blockIdx.x, tid = threadIdx.x;
    if (bid < 8192) {
        const size_t base = ((size_t)bid*256 + tid)*8;
        *reinterpret_cast<short8*>(xb + base) = cvt8(x + base);
    } else if (bid < 8448) {
        __shared__ short tr[64*68];
        const int bb = bid - 8192;
        const int dt = bb >> 4, et = bb & 15;
        const int d0 = dt*64, e0 = et*64;
        const int ein = tid & 63, din = tid >> 6;
        #pragma unroll
        for (int j = 0; j < 16; ++j) {
            const int dl = din + j*4;
            tr[ein*68 + dl] = f2b(VO[(size_t)(d0 + dl)*DIM + e0 + ein]);
        }
        __syncthreads();
        const int or_ = tid >> 4, oc = (tid & 15)*4;
        #pragma unroll
        for (int j = 0; j < 4; ++j) {
            const int el = or_ + j*16;
            short4v v;
            v[0]=tr[el*68+oc]; v[1]=tr[el*68+oc+1];
            v[2]=tr[el*68+oc+2]; v[3]=tr[el*68+oc+3];
            *reinterpret_cast<short4v*>(VOt + (size_t)(e0+el)*DIM + d0 + oc) = v;
        }
    } else {
        const int gid = (bid - 8448)*256 + tid;     // [0,16384)
        const int row = gid >> 7, c8 = (gid & 127)*8;
        const float* src = (row < 64 ? Qw + (size_t)row*DIM
                                     : Kw + (size_t)(row-64)*DIM) + c8;
        *reinterpret_cast<short8*>(Wb + (size_t)row*DIM + c8) = cvt8(src);
    }
}

// ---------------------------------------------------------------------------
// lr_proj2: D[t][r] = xb . Wb^T -> xq/xk bf16 [gt][64]. m97 structure.
// ---------------------------------------------------------------------------
__global__ __launch_bounds__(256, 4) void lr_proj2(const short* __restrict__ xb,
                                                   const short* __restrict__ Wb,
                                                   short* __restrict__ ws)
{
    __shared__ __align__(16) short As[128*64];
    __shared__ __align__(16) short Bs[128*64];
    const int t0 = blockIdx.x*128;
    const int tid = threadIdx.x, lane = tid & 63, w = tid >> 6;
    const int l15 = lane & 15, g = lane >> 4;
    const int wr = w >> 1, wc = w & 1;
    const short* Ab = xb + (size_t)t0*DIM;
    const short* Bb = Wb;
    const int srow = lane >> 3;
    const int skc  = ((lane & 7) ^ srow)*8;
    const int rx = l15 & 7;

    f32x4 acc[4][4] = {};
    #pragma unroll
    for (int j = 0; j < 4; ++j) {
        const int ch = 4*w + j, row = ch*8 + srow;
        gld16(Ab + (size_t)row*DIM + skc, &As[ch*512]);
        gld16(Bb + (size_t)row*DIM + skc, &Bs[ch*512]);
    }
    for (int kt = 0; kt < 16; ++kt) {
        __syncthreads();
        #pragma unroll
        for (int ks = 0; ks < 2; ++ks) {
            short8 af[4], bfr[4];
            #pragma unroll
            for (int mr = 0; mr < 4; ++mr)
                af[mr] = *reinterpret_cast<const short8*>(
                    &As[(wr*64 + mr*16 + l15)*64 + ((ks*4 + g) ^ rx)*8]);
            #pragma unroll
            for (int ct = 0; ct < 4; ++ct)
                bfr[ct] = *reinterpret_cast<const short8*>(
                    &Bs[(wc*64 + ct*16 + l15)*64 + ((ks*4 + g) ^ rx)*8]);
            #pragma unroll
            for (int mr = 0; mr < 4; ++mr)
                #pragma unroll
                for (int ct = 0; ct < 4; ++ct)
                    acc[mr][ct] = MFMA16(af[mr], bfr[ct], acc[mr][ct]);
        }
        if (kt < 15) {
            __syncthreads();
            const int k0 = (kt + 1)*64;
            #pragma unroll
            for (int j = 0; j < 4; ++j) {
                const int ch = 4*w + j, row = ch*8 + srow;
                gld16(Ab + (size_t)row*DIM + k0 + skc, &As[ch*512]);
                gld16(Bb + (size_t)row*DIM + k0 + skc, &Bs[ch*512]);
            }
        }
    }
    short* xqp = ws + XQ_OFF;
    short* xkp = ws + XK_OFF;
    #pragma unroll
    for (int mr = 0; mr < 4; ++mr)
        #pragma unroll
        for (int rr = 0; rr < 4; ++rr) {
            const int t = t0 + wr*64 + mr*16 + g*4 + rr;
            #pragma unroll
            for (int ct = 0; ct < 4; ++ct) {
                const int r = wc*64 + ct*16 + l15;
                const short v = f2b(acc[mr][ct][rr]);
                if (r < RANK) xqp[(size_t)t*RANK + r] = v;
                else          xkp[(size_t)t*RANK + r - RANK] = v;
            }
        }
}

// ---------------------------------------------------------------------------
// lr_vg8: vT = VOt . xb^T on the R7-verified 4-phase schedule (unchanged).
// ---------------------------------------------------------------------------
__global__ __launch_bounds__(512, 2) void lr_vg8(const short* __restrict__ VOt,
                                                 const short* __restrict__ xb,
                                                 short* __restrict__ vT)
{
    extern __shared__ __align__(16) short lds[];
    short* As = lds;
    short* Bs = lds + 32768;
    const int bid = blockIdx.x;
    const int xcd = bid & 7, jb = bid >> 3;
    const int et = xcd >> 1;
    const int bu = (xcd & 1)*32 + jb;
    const int b = bu >> 4, ut = bu & 15;
    const int e0 = et*256, u0 = ut*256;
    const int tid = threadIdx.x, lane = tid & 63, w = tid >> 6;
    const int wr = w >> 2, wc = w & 3;
    const int l15 = lane & 15, g = lane >> 4;
    const int rx = l15 & 7;

    const short* Ab = VOt + (size_t)e0*DIM;
    const short* Bb = xb + ((size_t)(b*SEQ) + u0)*DIM;

    int aA0[2], aA1[2], aB0[2], aB1[2];
    int dA0[2], dA1[2], dB0[2], dB1[2];
    #pragma unroll
    for (int j = 0; j < 2; ++j) {
        const int s = tid + 512*j;
        const int cl = s >> 6, v = s & 63;
        const int vr = v >> 3, vk = ((v & 7) ^ vr)*8;
        const int cA0 = (cl < 8) ? cl : cl + 8;
        const int cA1 = cA0 + 8;
        const int cB0 = ((cl >> 2) << 3) + (cl & 3);
        const int cB1 = cB0 + 4;
        aA0[j] = (cA0*8 + vr)*DIM + vk;  dA0[j] = cA0*512 + v*8;
        aA1[j] = (cA1*8 + vr)*DIM + vk;  dA1[j] = cA1*512 + v*8;
        aB0[j] = (cB0*8 + vr)*DIM + vk;  dB0[j] = cB0*512 + v*8;
        aB1[j] = (cB1*8 + vr)*DIM + vk;  dB1[j] = cB1*512 + v*8;
    }

    f32x4 acc[8][4] = {};
    short8 af[4][2], bf[4][2];

    #pragma unroll
    for (int j = 0; j < 2; ++j) gld16(Ab + aA0[j], &As[dA0[j]]);
    #pragma unroll
    for (int j = 0; j < 2; ++j) gld16(Bb + aB0[j], &Bs[dB0[j]]);
    #pragma unroll
    for (int j = 0; j < 2; ++j) gld16(Bb + aB1[j], &Bs[dB1[j]]);
    #pragma unroll
    for (int j = 0; j < 2; ++j) gld16(Ab + aA1[j], &As[dA1[j]]);
    asm volatile("s_waitcnt vmcnt(4)" ::: "memory");
    __builtin_amdgcn_s_barrier();
    __builtin_amdgcn_sched_barrier(0);

    for (int kt = 0; kt < 15; ++kt) {
        const int buf  = (kt & 1) ? 16384 : 0;
        const int nbuf = 16384 - buf;
        const int kn = (kt + 1)*64;
        const int arow = buf + (wr*128 + l15)*64;
        const int brow = buf + (wc*64 + l15)*64;
        // phase 0
        #pragma unroll
        for (int mf = 0; mf < 4; ++mf)
            #pragma unroll
            for (int ks = 0; ks < 2; ++ks)
                af[mf][ks] = *reinterpret_cast<const short8*>(
                    &As[arow + mf*1024 + ((ks*4 + g) ^ rx)*8]);
        #pragma unroll
        for (int nf = 0; nf < 2; ++nf)
            #pragma unroll
            for (int ks = 0; ks < 2; ++ks)
                bf[nf][ks] = *reinterpret_cast<const short8*>(
                    &Bs[brow + nf*1024 + ((ks*4 + g) ^ rx)*8]);
        #pragma unroll
        for (int j = 0; j < 2; ++j) gld16(Ab + aA0[j] + kn, &As[nbuf + dA0[j]]);
        __builtin_amdgcn_s_barrier();
        asm volatile("s_waitcnt lgkmcnt(0)" ::: "memory");
        __builtin_amdgcn_sched_barrier(0);
        __builtin_amdgcn_s_setprio(1);
        #pragma unroll
        for (int mf = 0; mf < 4; ++mf)
            #pragma unroll
            for (int nf = 0; nf < 2; ++nf)
                #pragma unroll
                for (int ks = 0; ks < 2; ++ks)
                    acc[mf][nf] = MFMA16(af[mf][ks], bf[nf][ks], acc[mf][nf]);
        __builtin_amdgcn_s_setprio(0);
        asm volatile("s_waitcnt vmcnt(4)" ::: "memory");
        __builtin_amdgcn_s_barrier();
        __builtin_amdgcn_sched_barrier(0);
        // phase 1
        #pragma unroll
        for (int nf = 2; nf < 4; ++nf)
            #pragma unroll
            for (int ks = 0; ks < 2; ++ks)
                bf[nf][ks] = *reinterpret_cast<const short8*>(
                    &Bs[brow + nf*1024 + ((ks*4 + g) ^ rx)*8]);
        #pragma unroll
        for (int j = 0; j < 2; ++j) gld16(Bb + aB0[j] + kn, &Bs[nbuf + dB0[j]]);
        __builtin_amdgcn_s_barrier();
        asm volatile("s_waitcnt lgkmcnt(0)" ::: "memory");
        __builtin_amdgcn_sched_barrier(0);
        __builtin_amdgcn_s_setprio(1);
        #pragma unroll
        for (int mf = 0; mf < 4; ++mf)
            #pragma unroll
            for (int nf = 2; nf < 4; ++nf)
                #pragma unroll
                for (int ks = 0; ks < 2; ++ks)
                    acc[mf][nf] = MFMA16(af[mf][ks], bf[nf][ks], acc[mf][nf]);
        __builtin_amdgcn_s_setprio(0);
        asm volatile("s_waitcnt vmcnt(4)" ::: "memory");
        __builtin_amdgcn_s_barrier();
        __builtin_amdgcn_sched_barrier(0);
        // phase 2
        #pragma unroll
        for (int mf = 0; mf < 4; ++mf)
            #pragma unroll
            for (int ks = 0; ks < 2; ++ks)
                af[mf][ks] = *reinterpret_cast<const short8*>(
                    &As[arow + 4096 + mf*1024 + ((ks*4 + g) ^ rx)*8]);
        #pragma unroll
        for (int j = 0; j < 2; ++j) gld16(Bb + aB1[j] + kn, &Bs[nbuf + dB1[j]]);
        __builtin_amdgcn_s_barrier();
        asm volatile("s_waitcnt lgkmcnt(0)" ::: "memory");
        __builtin_amdgcn_sched_barrier(0);
        __builtin_amdgcn_s_setprio(1);
        #pragma unroll
        for (int mf = 0; mf < 4; ++mf)
            #pragma unroll
            for (int nf = 0; nf < 2; ++nf)
                #pragma unroll
                for (int ks = 0; ks < 2; ++ks)
                    acc[mf+4][nf] = MFMA16(af[mf][ks], bf[nf][ks], acc[mf+4][nf]);
        __builtin_amdgcn_s_setprio(0);
        __builtin_amdgcn_s_barrier();
        __builtin_amdgcn_sched_barrier(0);
        // phase 3
        #pragma unroll
        for (int j = 0; j < 2; ++j) gld16(Ab + aA1[j] + kn, &As[nbuf + dA1[j]]);
        __builtin_amdgcn_s_setprio(1);
        #pragma unroll
        for (int mf = 0; mf < 4; ++mf)
            #pragma unroll
            for (int nf = 2; nf < 4; ++nf)
                #pragma unroll
                for (int ks = 0; ks < 2; ++ks)
                    acc[mf+4][nf] = MFMA16(af[mf][ks], bf[nf][ks], acc[mf+4][nf]);
        __builtin_amdgcn_s_setprio(0);
        asm volatile("s_waitcnt vmcnt(4)" ::: "memory");
        __builtin_amdgcn_s_barrier();
        __builtin_amdgcn_sched_barrier(0);
    }
    asm volatile("s_waitcnt vmcnt(0)" ::: "memory");
    __builtin_amdgcn_s_barrier();
    __builtin_amdgcn_sched_barrier(0);
    {
        const int arow = 16384 + (wr*128 + l15)*64;
        const int brow = 16384 + (wc*64 + l15)*64;
        #pragma unroll
        for (int mf = 0; mf < 4; ++mf)
            #pragma unroll
            for (int ks = 0; ks < 2; ++ks)
                af[mf][ks] = *reinterpret_cast<const short8*>(
                    &As[arow + mf*1024 + ((ks*4 + g) ^ rx)*8]);
        #pragma unroll
        for (int nf = 0; nf < 4; ++nf)
            #pragma unroll
            for (int ks = 0; ks < 2; ++ks)
                bf[nf][ks] = *reinterpret_cast<const short8*>(
                    &Bs[brow + nf*1024 + ((ks*4 + g) ^ rx)*8]);
        #pragma unroll
        for (int mf = 0; mf < 4; ++mf)
            #pragma unroll
            for (int nf = 0; nf < 4; ++nf)
                #pragma unroll
                for (int ks = 0; ks < 2; ++ks)
                    acc[mf][nf] = MFMA16(af[mf][ks], bf[nf][ks], acc[mf][nf]);
        #pragma unroll
        for (int mf = 0; mf < 4; ++mf)
            #pragma unroll
            for (int ks = 0; ks < 2; ++ks)
                af[mf][ks] = *reinterpret_cast<const short8*>(
                    &As[arow + 4096 + mf*1024 + ((ks*4 + g) ^ rx)*8]);
        #pragma unroll
        for (int mf = 0; mf < 4; ++mf)
            #pragma unroll
            for (int nf = 0; nf < 4; ++nf)
                #pragma unroll
                for (int ks = 0; ks < 2; ++ks)
                    acc[mf+4][nf] = MFMA16(af[mf][ks], bf[nf][ks], acc[mf+4][nf]);
    }
    #pragma unroll
    for (int mf = 0; mf < 8; ++mf)
        #pragma unroll
        for (int rr = 0; rr < 4; ++rr) {
            const int e = e0 + wr*128 + mf*16 + g*4 + rr;
            short* orow = vT + ((size_t)(b*DIM) + e)*SEQ + u0 + wc*64;
            #pragma unroll
            for (int nf = 0; nf < 4; ++nf)
                orow[nf*16 + l15] = f2b(acc[mf][nf][rr]);
        }
}

// ---------------------------------------------------------------------------
// lr_vgemm2: fallback (m97 128^2, K=1024) if dynamic-LDS attr fails.
// ---------------------------------------------------------------------------
__global__ __launch_bounds__(256, 4) void lr_vgemm2(const short* __restrict__ VOt,
                                                    const short* __restrict__ xb,
                                                    short* __restrict__ vT)
{
    __shared__ __align__(16) short As[128*64];
    __shared__ __align__(16) short Bs[128*64];
    const int i = blockIdx.x;
    const int etile = i & 7, j = i >> 3;
    const int ut = j & 31, b = j >> 5;
    const int e0 = etile*128, u0 = ut*128;
    const int tid = threadIdx.x, lane = tid & 63, w = tid >> 6;
    const int l15 = lane & 15, g = lane >> 4;
    const int wr = w >> 1, wc = w & 1;
    const short* Ab = VOt + (size_t)e0*DIM;
    const short* Bb = xb + ((size_t)(b*SEQ) + u0)*DIM;
    const int srow = lane >> 3;
    const int skc  = ((lane & 7) ^ srow)*8;
    const int rx = l15 & 7;

    f32x4 acc[4][4] = {};
    #pragma unroll
    for (int jj = 0; jj < 4; ++jj) {
        const int ch = 4*w + jj, row = ch*8 + srow;
        gld16(Ab + (size_t)row*DIM + skc, &As[ch*512]);
        gld16(Bb + (size_t)row*DIM + skc, &Bs[ch*512]);
    }
    for (int kt = 0; kt < 16; ++kt) {
        __syncthreads();
        #pragma unroll
        for (int ks = 0; ks < 2; ++ks) {
            short8 af[4], bfr[4];
            #pragma unroll
            for (int mr = 0; mr < 4; ++mr)
                af[mr] = *reinterpret_cast<const short8*>(
                    &As[(wr*64 + mr*16 + l15)*64 + ((ks*4 + g) ^ rx)*8]);
            #pragma unroll
            for (int ct = 0; ct < 4; ++ct)
                bfr[ct] = *reinterpret_cast<const short8*>(
                    &Bs[(wc*64 + ct*16 + l15)*64 + ((ks*4 + g) ^ rx)*8]);
            #pragma unroll
            for (int mr = 0; mr < 4; ++mr)
                #pragma unroll
                for (int ct = 0; ct < 4; ++ct)
                    acc[mr][ct] = MFMA16(af[mr], bfr[ct], acc[mr][ct]);
        }
        if (kt < 15) {
            __syncthreads();
            const int k0 = (kt + 1)*64;
            #pragma unroll
            for (int jj = 0; jj < 4; ++jj) {
                const int ch = 4*w + jj, row = ch*8 + srow;
                gld16(Ab + (size_t)row*DIM + k0 + skc, &As[ch*512]);
                gld16(Bb + (size_t)row*DIM + k0 + skc, &Bs[ch*512]);
            }
        }
    }
    #pragma unroll
    for (int mr = 0; mr < 4; ++mr)
        #pragma unroll
        for (int rr = 0; rr < 4; ++rr) {
            const int e = e0 + wr*64 + mr*16 + g*4 + rr;
            short* orow = vT + ((size_t)(b*DIM) + e)*SEQ + u0 + wc*64;
            #pragma unroll
            for (int ct = 0; ct < 4; ++ct)
                orow[ct*16 + l15] = f2b(acc[mr][ct][rr]);
        }
}

// ---------------------------------------------------------------------------
// lr_pexp: P_un[gq][u] = exp2(S*cl) bf16 + partial row sums ps[gq][ut].
// ---------------------------------------------------------------------------
__global__ __launch_bounds__(256, 4) void lr_pexp(const short* __restrict__ ws,
                                                  short* __restrict__ P,
                                                  float* __restrict__ ps)
{
    __shared__ __align__(16) short ptile[128*136];
    __shared__ float sred[4][128];
    const int i = blockIdx.x;
    const int qt = i >> 5, ut = i & 31;
    const int b = qt >> 5;
    const int tid = threadIdx.x, lane = tid & 63, w = tid >> 6;
    const int l15 = lane & 15, g = lane >> 4;
    const float cl = 0.045084220f;   // log2(e)/32
    const int q0 = qt*128;

    const short* xqb = ws + XQ_OFF + (size_t)q0*RANK;
    const short* xkb = ws + XK_OFF + ((size_t)(b*SEQ) + ut*128)*RANK;

    f32x4 acc[2][8] = {};
    #pragma unroll
    for (int ks = 0; ks < 2; ++ks) {
        short8 ak[2], bq[8];
        #pragma unroll
        for (int mr = 0; mr < 2; ++mr)
            ak[mr] = *reinterpret_cast<const short8*>(
                xkb + (size_t)(32*w + mr*16 + l15)*RANK + ks*32 + g*8);
        #pragma unroll
        for (int ct = 0; ct < 8; ++ct)
            bq[ct] = *reinterpret_cast<const short8*>(
                xqb + (size_t)(ct*16 + l15)*RANK + ks*32 + g*8);
        #pragma unroll
        for (int mr = 0; mr < 2; ++mr)
            #pragma unroll
            for (int ct = 0; ct < 8; ++ct)
                acc[mr][ct] = MFMA16(ak[mr], bq[ct], acc[mr][ct]);
    }
    float s[8] = {0.f,0.f,0.f,0.f,0.f,0.f,0.f,0.f};
    #pragma unroll
    for (int mr = 0; mr < 2; ++mr)
        #pragma unroll
        for (int ct = 0; ct < 8; ++ct) {
            short4v pk;
            #pragma unroll
            for (int r = 0; r < 4; ++r) {
                const short pb = f2b(__builtin_amdgcn_exp2f(acc[mr][ct][r]*cl));
                pk[r] = pb;
                s[ct] += b2f(pb);
            }
            *reinterpret_cast<short4v*>(
                &ptile[(ct*16 + l15)*136 + 32*w + mr*16 + g*4]) = pk;
        }
    #pragma unroll
    for (int ct = 0; ct < 8; ++ct) {
        s[ct] += __shfl_xor(s[ct], 16);
        s[ct] += __shfl_xor(s[ct], 32);
    }
    if (g == 0) {
        #pragma unroll
        for (int ct = 0; ct < 8; ++ct) sred[w][ct*16 + l15] = s[ct];
    }
    __syncthreads();
    #pragma unroll
    for (int j = 0; j < 8; ++j) {
        const int id = tid + 256*j;
        const int row = id >> 4, seg = id & 15;
        const uint4 v = *reinterpret_cast<const uint4*>(&ptile[row*136 + seg*8]);
        *reinterpret_cast<uint4*>(
            P + (size_t)(q0 + row)*SEQ + ut*128 + seg*8) = v;
    }
    if (tid < 128)
        ps[(size_t)(q0 + tid)*32 + ut] =
            sred[0][tid] + sred[1][tid] + sred[2][tid] + sred[3][tid];
}

// ---------------------------------------------------------------------------
// lr_psum (fallback path only): linv[gq] = 1 / sum_ut ps[gq][ut].
// ---------------------------------------------------------------------------
__global__ __launch_bounds__(256) void lr_psum(const float* __restrict__ ps,
                                               float* __restrict__ linv)
{
    const int gq = blockIdx.x*256 + threadIdx.x;
    const float* p = ps + (size_t)gq*32;
    float s = 0.f;
    #pragma unroll
    for (int j = 0; j < 32; ++j) s += p[j];
    linv[gq] = 1.0f / s;
}

// ---------------------------------------------------------------------------
// lr_pv8: 256x256x64 ledger-verified 4-phase GEMM (R8 schedule, REVERTED
// from R9's deep pipeline which regressed 122->132us). Half-tile order
// Ah0,Bh0,Bh1,Ah1; vmcnt(4) at end of ph0/ph1/ph3; psum folded in prologue
// with vmcnt(0) ledger-clean before first gld16.
// ---------------------------------------------------------------------------
__global__ __launch_bounds__(512, 2) void lr_pv8(const short* __restrict__ P,
                                                 const short* __restrict__ vT,
                                                 const float* __restrict__ ps,
                                                 float* __restrict__ out)
{
    extern __shared__ __align__(16) short lds[];
    __shared__ float linv_lds[256];
    short* As = lds;
    short* Bs = lds + 32768;
    const int bid = blockIdx.x;
    const int qt = (bid & 7)*8 + (bid >> 5);
    const int nt = (bid >> 3) & 3;
    const int q0 = qt*256, d0 = nt*256, b = qt >> 4;
    const int tid = threadIdx.x, lane = tid & 63, w = tid >> 6;
    const int wr = w >> 2, wc = w & 3;
    const int l15 = lane & 15, g = lane >> 4;
    const int rx = l15 & 7;

    // folded psum: linv for this block's 256 q rows
    if (tid < 256) {
        const float* pp = ps + (size_t)(q0 + tid)*32;
        float s = 0.f;
        #pragma unroll
        for (int jj = 0; jj < 32; ++jj) s += pp[jj];
        linv_lds[tid] = 1.0f / s;
    }
    asm volatile("s_waitcnt vmcnt(0)" ::: "memory");   // clean vmcnt ledger
    __builtin_amdgcn_sched_barrier(0);

    const short* Ab = P + (size_t)q0*SEQ;
    const short* Bb = vT + ((size_t)(b*DIM) + d0)*SEQ;

    int aA0[2], aA1[2], aB0[2], aB1[2];
    int dA0[2], dA1[2], dB0[2], dB1[2];
    #pragma unroll
    for (int j = 0; j < 2; ++j) {
        const int s = tid + 512*j;
        const int cl = s >> 6, v = s & 63;
        const int vr = v >> 3, vk = ((v & 7) ^ vr)*8;
        const int cA0 = (cl < 8) ? cl : cl + 8;
        const int cA1 = cA0 + 8;
        const int cB0 = ((cl >> 2) << 3) + (cl & 3);
        const int cB1 = cB0 + 4;
        aA0[j] = (cA0*8 + vr)*SEQ + vk;  dA0[j] = cA0*512 + v*8;
        aA1[j] = (cA1*8 + vr)*SEQ + vk;  dA1[j] = cA1*512 + v*8;
        aB0[j] = (cB0*8 + vr)*SEQ + vk;  dB0[j] = cB0*512 + v*8;
        aB1[j] = (cB1*8 + vr)*SEQ + vk;  dB1[j] = cB1*512 + v*8;
    }

    f32x4 acc[8][4] = {};
    short8 af[4][2], bf[4][2];

    #pragma unroll
    for (int j = 0; j < 2; ++j) gld16(Ab + aA0[j], &As[dA0[j]]);
    #pragma unroll
    for (int j = 0; j < 2; ++j) gld16(Bb + aB0[j], &Bs[dB0[j]]);
    #pragma unroll
    for (int j = 0; j < 2; ++j) gld16(Bb + aB1[j], &Bs[dB1[j]]);
    #pragma unroll
    for (int j = 0; j < 2; ++j) gld16(Ab + aA1[j], &As[dA1[j]]);
    asm volatile("s_waitcnt vmcnt(4)" ::: "memory");
    __builtin_amdgcn_s_barrier();
    __builtin_amdgcn_sched_barrier(0);

    for (int kt = 0; kt < 63; ++kt) {
        const int buf  = (kt & 1) ? 16384 : 0;
        const int nbuf = 16384 - buf;
        const int kn = (kt + 1)*64;
        const int arow = buf + (wr*128 + l15)*64;
        const int brow = buf + (wc*64 + l15)*64;
        // phase 0
        #pragma unroll
        for (int mf = 0; mf < 4; ++mf)
            #pragma unroll
            for (int ks = 0; ks < 2; ++ks)
                af[mf][ks] = *reinterpret_cast<const short8*>(
                    &As[arow + mf*1024 + ((ks*4 + g) ^ rx)*8]);
        #pragma unroll
        for (int nf = 0; nf < 2; ++nf)
            #pragma unroll
            for (int ks = 0; ks < 2; ++ks)
                bf[nf][ks] = *reinterpret_cast<const short8*>(
                    &Bs[brow + nf*1024 + ((ks*4 + g) ^ rx)*8]);
        #pragma unroll
        for (int j = 0; j < 2; ++j) gld16(Ab + aA0[j] + kn, &As[nbuf + dA0[j]]);
        __builtin_amdgcn_s_barrier();
        asm volatile("s_waitcnt lgkmcnt(0)" ::: "memory");
        __builtin_amdgcn_sched_barrier(0);
        __builtin_amdgcn_s_setprio(1);
        #pragma unroll
        for (int mf = 0; mf < 4; ++mf)
            #pragma unroll
            for (int nf = 0; nf < 2; ++nf)
                #pragma unroll
                for (int ks = 0; ks < 2; ++ks)
                    acc[mf][nf] = MFMA16(af[mf][ks], bf[nf][ks], acc[mf][nf]);
        __builtin_amdgcn_s_setprio(0);
        asm volatile("s_waitcnt vmcnt(4)" ::: "memory");
        __builtin_amdgcn_s_barrier();
        __builtin_amdgcn_sched_barrier(0);
        // phase 1
        #pragma unroll
        for (int nf = 2; nf < 4; ++nf)
            #pragma unroll
            for (int ks = 0; ks < 2; ++ks)
                bf[nf][ks] = *reinterpret_cast<const short8*>(
                    &Bs[brow + nf*1024 + ((ks*4 + g) ^ rx)*8]);
        #pragma unroll
        for (int j = 0; j < 2; ++j) gld16(Bb + aB0[j] + kn, &Bs[nbuf + dB0[j]]);
        __builtin_amdgcn_s_barrier();
        asm volatile("s_waitcnt lgkmcnt(0)" ::: "memory");
        __builtin_amdgcn_sched_barrier(0);
        __builtin_amdgcn_s_setprio(1);
        #pragma unroll
        for (int mf = 0; mf < 4; ++mf)
            #pragma unroll
            for (int nf = 2; nf < 4; ++nf)
                #pragma unroll
                for (int ks = 0; ks < 2; ++ks)
                    acc[mf][nf] = MFMA16(af[mf][ks], bf[nf][ks], acc[mf][nf]);
        __builtin_amdgcn_s_setprio(0);
        asm volatile("s_waitcnt vmcnt(4)" ::: "memory");
        __builtin_amdgcn_s_barrier();
        __builtin_amdgcn_sched_barrier(0);
        // phase 2
        #pragma unroll
        for (int mf = 0; mf < 4; ++mf)
            #pragma unroll
            for (int ks = 0; ks < 2; ++ks)
                af[mf][ks] = *reinterpret_cast<const short8*>(
                    &As[arow + 4096 + mf*1024 + ((ks*4 + g) ^ rx)*8]);
        #pragma unroll
        for (int j = 0; j < 2; ++j) gld16(Bb + aB1[j] + kn, &Bs[nbuf + dB1[j]]);
        __builtin_amdgcn_s_barrier();
        asm volatile("s_waitcnt lgkmcnt(0)" ::: "memory");
        __builtin_amdgcn_sched_barrier(0);
        __builtin_amdgcn_s_setprio(1);
        #pragma unroll
        for (int mf = 0; mf < 4; ++mf)
            #pragma unroll
            for (int nf = 0; nf < 2; ++nf)
                #pragma unroll
                for (int ks = 0; ks < 2; ++ks)
                    acc[mf+4][nf] = MFMA16(af[mf][ks], bf[nf][ks], acc[mf+4][nf]);
        __builtin_amdgcn_s_setprio(0);
        __builtin_amdgcn_s_barrier();
        __builtin_amdgcn_sched_barrier(0);
        // phase 3
        #pragma unroll
        for (int j = 0; j < 2; ++j) gld16(Ab + aA1[j] + kn, &As[nbuf + dA1[j]]);
        __builtin_amdgcn_s_setprio(1);
        #pragma unroll
        for (int mf = 0; mf < 4; ++mf)
            #pragma unroll
            for (int nf = 2; nf < 4; ++nf)
                #pragma unroll
                for (int ks = 0; ks < 2; ++ks)
                    acc[mf+4][nf] = MFMA16(af[mf][ks], bf[nf][ks], acc[mf+4][nf]);
        __builtin_amdgcn_s_setprio(0);
        asm volatile("s_waitcnt vmcnt(4)" ::: "memory");
        __builtin_amdgcn_s_barrier();
        __builtin_amdgcn_sched_barrier(0);
    }
    asm volatile("s_waitcnt vmcnt(0)" ::: "memory");
    __builtin_amdgcn_s_barrier();
    __builtin_amdgcn_sched_barrier(0);
    {
        const int arow = 16384 + (wr*128 + l15)*64;
        const int brow = 16384 + (wc*64 + l15)*64;
        #pragma unroll
        for (int mf = 0; mf < 4; ++mf)
            #pragma unroll
            for (int ks = 0; ks < 2; ++ks)
                af[mf][ks] = *reinterpret_cast<const short8*>(
                    &As[arow + mf*1024 + ((ks*4 + g) ^ rx)*8]);
        #pragma unroll
        for (int nf = 0; nf < 4; ++nf)
            #pragma unroll
            for (int ks = 0; ks < 2; ++ks)
                bf[nf][ks] = *reinterpret_cast<const short8*>(
                    &Bs[brow + nf*1024 + ((ks*4 + g) ^ rx)*8]);
        #pragma unroll
        for (int mf = 0; mf < 4; ++mf)
            #pragma unroll
            for (int nf = 0; nf < 4; ++nf)
                #pragma unroll
                for (int ks = 0; ks < 2; ++ks)
                    acc[mf][nf] = MFMA16(af[mf][ks], bf[nf][ks], acc[mf][nf]);
        #pragma unroll
        for (int mf = 0; mf < 4; ++mf)
            #pragma unroll
            for (int ks = 0; ks < 2; ++ks)
                af[mf][ks] = *reinterpret_cast<const short8*>(
                    &As[arow + 4096 + mf*1024 + ((ks*4 + g) ^ rx)*8]);
        #pragma unroll
        for (int mf = 0; mf < 4; ++mf)
            #pragma unroll
            for (int nf = 0; nf < 4; ++nf)
                #pragma unroll
                for (int ks = 0; ks < 2; ++ks)
                    acc[mf+4][nf] = MFMA16(af[mf][ks], bf[nf][ks], acc[mf+4][nf]);
    }
    #pragma unroll
    for (int mf = 0; mf < 8; ++mf)
        #pragma unroll
        for (int rr = 0; rr < 4; ++rr) {
            const int ql = wr*128 + mf*16 + g*4 + rr;
            const float sc = linv_lds[ql];
            float* rp = out + (size_t)(q0 + ql)*DIM + d0 + wc*64;
            #pragma unroll
            for (int nf = 0; nf < 4; ++nf)
                rp[nf*16 + l15] = acc[mf][nf][rr]*sc;
        }
}

// ---------------------------------------------------------------------------
// lr_pv: R5 2-phase 128^2 GEMM -- fallback if 128KB dynamic LDS unavailable.
// ---------------------------------------------------------------------------
__global__ __launch_bounds__(256, 4) void lr_pv(const short* __restrict__ P,
                                                const short* __restrict__ vT,
                                                const float* __restrict__ linv,
                                                float* __restrict__ out)
{
    __shared__ __align__(16) short As[128*64];
    __shared__ __align__(16) short Bs[128*64];
    const int i = blockIdx.x;
    const int qlo = i & 7, j = i >> 3;
    const int nt = j & 7, qhi = j >> 3;
    const int qt = qhi*8 + qlo;
    const int q0 = qt*128, d0 = nt*128, b = qt >> 5;
    const int tid = threadIdx.x, lane = tid & 63, w = tid >> 6;
    const int l15 = lane & 15, g = lane >> 4;
    const int wr = w >> 1, wc = w & 1;

    const short* Ab = P + (size_t)q0*SEQ;
    const short* Bb = vT + ((size_t)(b*DIM) + d0)*SEQ;
    const int srow = lane >> 3;
    const int skc  = ((lane & 7) ^ srow)*8;
    const int rx = l15 & 7;

    f32x4 acc[4][4] = {};
    #pragma unroll
    for (int jj = 0; jj < 4; ++jj) {
        const int ch = 4*w + jj, row = ch*8 + srow;
        gld16(Ab + (size_t)row*SEQ + skc, &As[ch*512]);
        gld16(Bb + (size_t)row*SEQ + skc, &Bs[ch*512]);
    }
    for (int kt = 0; kt < 64; ++kt) {
        __syncthreads();
        #pragma unroll
        for (int ks = 0; ks < 2; ++ks) {
            short8 af[4], bfr[4];
            #pragma unroll
            for (int mr = 0; mr < 4; ++mr)
                af[mr] = *reinterpret_cast<const short8*>(
                    &As[(wr*64 + mr*16 + l15)*64 + ((ks*4 + g) ^ rx)*8]);
            #pragma unroll
            for (int ct = 0; ct < 4; ++ct)
                bfr[ct] = *reinterpret_cast<const short8*>(
                    &Bs[(wc*64 + ct*16 + l15)*64 + ((ks*4 + g) ^ rx)*8]);
            #pragma unroll
            for (int mr = 0; mr < 4; ++mr)
                #pragma unroll
                for (int ct = 0; ct < 4; ++ct)
                    acc[mr][ct] = MFMA16(af[mr], bfr[ct], acc[mr][ct]);
        }
        if (kt < 63) {
            __syncthreads();
            const int k0 = (kt + 1)*64;
            #pragma unroll
            for (int jj = 0; jj < 4; ++jj) {
                const int ch = 4*w + jj, row = ch*8 + srow;
                gld16(Ab + (size_t)row*SEQ + k0 + skc, &As[ch*512]);
                gld16(Bb + (size_t)row*SEQ + k0 + skc, &Bs[ch*512]);
            }
        }
    }
    #pragma unroll
    for (int mr = 0; mr < 4; ++mr)
        #pragma unroll
        for (int rr = 0; rr < 4; ++rr) {
            const int q = q0 + wr*64 + mr*16 + g*4 + rr;
            const float sc = linv[q];
            float* rp = out + (size_t)q*DIM + d0 + wc*64;
            #pragma unroll
            for (int ct = 0; ct < 4; ++ct)
                rp[ct*16 + l15] = acc[mr][ct][rr]*sc;
        }
}

// ===========================================================================
// Fallback path (used only if ws_size too small): R3 kernels, unchanged.
// ===========================================================================
__global__ __launch_bounds__(256) void lr_proj(const float* __restrict__ x,
                                               const float* __restrict__ Qw,
                                               const float* __restrict__ Kw,
                                               short* __restrict__ ws)
{
    __shared__ __align__(16) short ldsB[64*40];
    const int i = blockIdx.x;
    const int ttile = i & 63, b = i >> 6;
    const int tid = threadIdx.x, lane = tid & 63, w = tid >> 6;
    const int l15 = lane & 15, g = lane >> 4;
    const int t0 = ttile * 64;

    f32x4 acc[2][4] = {};
    for (int e0 = 0; e0 < DIM; e0 += 32) {
        const int tr = tid >> 2, seg = tid & 3;
        const float* px = x + (size_t)(b*SEQ + t0 + tr)*DIM + e0 + seg*8;
        const float4 f0 = *reinterpret_cast<const float4*>(px);
        const float4 f1 = *reinterpret_cast<const float4*>(px + 4);
        __syncthreads();
        {
            short* d = &ldsB[tr*40 + seg*8];
            d[0]=f2b(f0.x); d[1]=f2b(f0.y); d[2]=f2b(f0.z); d[3]=f2b(f0.w);
            d[4]=f2b(f1.x); d[5]=f2b(f1.y); d[6]=f2b(f1.z); d[7]=f2b(f1.w);
        }
        __syncthreads();
        #pragma unroll
        for (int mr = 0; mr < 2; ++mr) {
            const int r = 32*w + mr*16 + l15;
            const float* wp = (r < RANK ? Qw + (size_t)r*DIM
                                        : Kw + (size_t)(r - RANK)*DIM) + e0 + g*8;
            const short8 a = cvt8(wp);
            #pragma unroll
            for (int ct = 0; ct < 4; ++ct) {
                const short8 bb = *reinterpret_cast<const short8*>(
                    &ldsB[(ct*16 + l15)*40 + g*8]);
                acc[mr][ct] = MFMA16(a, bb, acc[mr][ct]);
            }
        }
    }
    short* xqp = ws + XQ_OFF;
    short* xkp = ws + XK_OFF;
    #pragma unroll
    for (int mr = 0; mr < 2; ++mr) {
        const int rb = 32*w + mr*16 + g*4;
        short* base = (rb < RANK) ? (xqp + rb) : (xkp + (rb - RANK));
        #pragma unroll
        for (int ct = 0; ct < 4; ++ct) {
            const int t = t0 + ct*16 + l15;
            short4v pk;
            pk[0]=f2b(acc[mr][ct][0]); pk[1]=f2b(acc[mr][ct][1]);
            pk[2]=f2b(acc[mr][ct][2]); pk[3]=f2b(acc[mr][ct][3]);
            *reinterpret_cast<short4v*>(base + (size_t)(b*SEQ + t)*RANK) = pk;
        }
    }
}

__global__ __launch_bounds__(256) void lr_vgemm(const float* __restrict__ x,
                                                const float* __restrict__ VO,
                                                short* __restrict__ ws)
{
    short* vT = ws + VT_OFF;
    __shared__ __align__(16) short ldsA[128*40];
    __shared__ __align__(16) short ldsB[128*40];
    const int i = blockIdx.x;
    const int dtile = i & 7, utile = (i >> 3) & 31, b = i >> 8;
    const int d0 = dtile*128, u0 = utile*128;
    const int tid = threadIdx.x, lane = tid & 63, w = tid >> 6;
    const int l15 = lane & 15, g = lane >> 4;
    const int wr = w >> 1, wc = w & 1;

    f32x4 acc[4][4] = {};
    for (int e0 = 0; e0 < DIM; e0 += 32) {
        const int dcol = tid & 127, erg = (tid >> 7)*16;
        float va[16];
        #pragma unroll
        for (int j = 0; j < 16; ++j)
            va[j] = VO[(size_t)(e0 + erg + j)*DIM + d0 + dcol];
        const int ur = tid >> 1, esg = (tid & 1)*16;
        const float* pb = x + (size_t)(b*SEQ + u0 + ur)*DIM + e0 + esg;
        float4 vb0 = reinterpret_cast<const float4*>(pb)[0];
        float4 vb1 = reinterpret_cast<const float4*>(pb)[1];
        float4 vb2 = reinterpret_cast<const float4*>(pb)[2];
        float4 vb3 = reinterpret_cast<const float4*>(pb)[3];
        __syncthreads();
        #pragma unroll
        for (int j = 0; j < 16; ++j) ldsA[dcol*40 + erg + j] = f2b(va[j]);
        {
            short* d = &ldsB[ur*40 + esg];
            d[0]=f2b(vb0.x); d[1]=f2b(vb0.y); d[2]=f2b(vb0.z); d[3]=f2b(vb0.w);
            d[4]=f2b(vb1.x); d[5]=f2b(vb1.y); d[6]=f2b(vb1.z); d[7]=f2b(vb1.w);
            d[8]=f2b(vb2.x); d[9]=f2b(vb2.y); d[10]=f2b(vb2.z); d[11]=f2b(vb2.w);
            d[12]=f2b(vb3.x); d[13]=f2b(vb3.y); d[14]=f2b(vb3.z); d[15]=f2b(vb3.w);
        }
        __syncthreads();
        short8 af[4], bfr[4];
        #pragma unroll
        for (int mr = 0; mr < 4; ++mr)
            af[mr] = *reinterpret_cast<const short8*>(
                &ldsA[(wr*64 + mr*16 + l15)*40 + g*8]);
        #pragma unroll
        for (int ct = 0; ct < 4; ++ct)
            bfr[ct] = *reinterpret_cast<const short8*>(
                &ldsB[(wc*64 + ct*16 + l15)*40 + g*8]);
        #pragma unroll
        for (int mr = 0; mr < 4; ++mr)
            #pragma unroll
            for (int ct = 0; ct < 4; ++ct)
                acc[mr][ct] = MFMA16(af[mr], bfr[ct], acc[mr][ct]);
    }
    #pragma unroll
    for (int mr = 0; mr < 4; ++mr)
        #pragma unroll
        for (int rr = 0; rr < 4; ++rr) {
            const int d = d0 + wr*64 + mr*16 + g*4 + rr;
            short* orow = vT + (size_t)(b*DIM + d)*SEQ + u0 + wc*64;
            #pragma unroll
            for (int ct = 0; ct < 4; ++ct)
                orow[ct*16 + l15] = f2b(acc[mr][ct][rr]);
        }
}

__global__ __launch_bounds__(256) void lr_stats(const short* __restrict__ ws,
                                                float* __restrict__ pm,
                                                float* __restrict__ pl)
{
    const short* xq = ws + XQ_OFF;
    const short* xk = ws + XK_OFF;
    const int i = blockIdx.x;
    const int us = i & 3, qtile = (i >> 2) & 63, b = i >> 8;
    const int tid = threadIdx.x, lane = tid & 63, w = tid >> 6;
    const int l15 = lane & 15, g = lane >> 4;
    const float cl = 0.045084220f;

    short8 qb0, qb1;
    {
        const short* p = xq + (size_t)(b*SEQ + qtile*64 + 16*w + l15)*RANK + g*8;
        qb0 = *reinterpret_cast<const short8*>(p);
        qb1 = *reinterpret_cast<const short8*>(p + 32);
    }
    const short* kb = xk + (size_t)b*SEQ*RANK;

    float m = -3.0e38f, l = 0.f;
    for (int it = 0; it < 16; ++it) {
        const int ub = us*1024 + it*64;
        f32x4 S[4];
        #pragma unroll
        for (int t = 0; t < 4; ++t) {
            const short* kp = kb + (size_t)(ub + 16*t + l15)*RANK + g*8;
            const short8 a0 = *reinterpret_cast<const short8*>(kp);
            const short8 a1 = *reinterpret_cast<const short8*>(kp + 32);
            f32x4 z = {};
            z = MFMA16(a0, qb0, z);
            z = MFMA16(a1, qb1, z);
            S[t] = z;
        }
        float mt = S[0][0];
        #pragma unroll
        for (int t = 0; t < 4; ++t)
            #pragma unroll
            for (int r = 0; r < 4; ++r) mt = fmaxf(mt, S[t][r]);
        const float mn = fmaxf(m, mt);
        l *= __builtin_amdgcn_exp2f((m - mn)*cl);
        const float mc = mn*cl;
        #pragma unroll
        for (int t = 0; t < 4; ++t)
            #pragma unroll
            for (int r = 0; r < 4; ++r)
                l += __builtin_amdgcn_exp2f(__builtin_fmaf(S[t][r], cl, -mc));
        m = mn;
    }
    #pragma unroll
    for (int mask = 16; mask <= 32; mask <<= 1) {
        const float mo = __shfl_xor(m, mask), lo = __shfl_xor(l, mask);
        const float mn = fmaxf(m, mo);
        l = l*__builtin_amdgcn_exp2f((m - mn)*cl)
          + lo*__builtin_amdgcn_exp2f((mo - mn)*cl);
        m = mn;
    }
    if (g == 0) {
        const int idx = (b*SEQ + qtile*64 + 16*w + l15)*4 + us;
        pm[idx] = m; pl[idx] = l;
    }
}

__global__ __launch_bounds__(256, 4) void lr_flash(const short* __restrict__ ws,
                                                   const float* __restrict__ pm,
                                                   const float* __restrict__ pl,
                                                   float* __restrict__ out)
{
    const short* xq = ws + XQ_OFF;
    const short* xk = ws + XK_OFF;
    const short* vT = ws + VT_OFF;
    __shared__ __align__(16) short vlds[128*64];
    __shared__ __align__(16) short plds[32*64];
    const int i = blockIdx.x;
    const int xcd = i & 7, slot = i >> 3;
    const int combo = xcd + 8*(slot >> 6);
    const int qtile = slot & 63;
    const int b = combo >> 2, dch = combo & 3;
    const int tid = threadIdx.x, lane = tid & 63, w = tid >> 6;
    const int l15 = lane & 15, g = lane >> 4;
    const float cl = 0.045084220f;

    float mC;
    {
        const int base = (b*SEQ + qtile*64 + 16*w + l15)*4;
        const float m0 = pm[base+0], m1 = pm[base+1];
        const float m2 = pm[base+2], m3 = pm[base+3];
        const float mm = fmaxf(fmaxf(m0, m1), fmaxf(m2, m3));
        const float l = pl[base+0]*__builtin_amdgcn_exp2f((m0-mm)*cl)
                      + pl[base+1]*__builtin_amdgcn_exp2f((m1-mm)*cl)
                      + pl[base+2]*__builtin_amdgcn_exp2f((m2-mm)*cl)
                      + pl[base+3]*__builtin_amdgcn_exp2f((m3-mm)*cl);
        mC = -(mm*cl + __builtin_amdgcn_logf(l));
    }
    short8 qb0, qb1;
    {
        const short* p = xq + (size_t)(b*SEQ + qtile*64 + 16*w + l15)*RANK + g*8;
        qb0 = *reinterpret_cast<const short8*>(p);
        qb1 = *reinterpret_cast<const short8*>(p + 32);
    }
    const short* vbase = vT + ((size_t)b*DIM + dch*256)*SEQ;
    const short* kr = xk + (size_t)b*SEQ*RANK + l15*RANK + g*8;
    const int r7 = l15 >> 1;
    const int st_dst = (tid >> 3)*64 + (((tid & 7) ^ ((tid >> 3) & 7))*8);
    const int st_src = (tid >> 2)*SEQ + (tid & 3)*8;
    const int a_base = r7*64 + ((((l15 & 1)*4 + g) ^ r7)*8);
    const int b_base = (32*w + r7)*64 + ((((l15 & 1)*4 + g) ^ r7)*8);
    const int chv = (l15 & 1)*4 + (g >> 1);
    const int pw0 = (8*w + r7)*64 + ((chv ^ r7)*8)       + (g & 1)*4;
    const int pw1 = (8*w + r7)*64 + (((chv + 2) ^ r7)*8) + (g & 1)*4;

    uint4 sreg[4];
    #pragma unroll
    for (int c = 0; c < 4; ++c)
        sreg[c] = *reinterpret_cast<const uint4*>(vbase + st_src + (size_t)c*64*SEQ);
    #pragma unroll
    for (int c = 0; c < 4; ++c)
        *reinterpret_cast<uint4*>(&vlds[st_dst + 2048*c]) = sreg[c];

    f32x4 O[16] = {};
    for (int ub = 0; ub < SEQ; ub += 32) {
        const bool more = (ub + 32 < SEQ);
        if (more) {
            #pragma unroll
            for (int c = 0; c < 4; ++c)
                sreg[c] = *reinterpret_cast<const uint4*>(
                    vbase + st_src + ub + 32 + (size_t)c*64*SEQ);
        }
        #pragma unroll
        for (int t = 0; t < 2; ++t) {
            const short* kp = kr + (size_t)(ub + 16*t)*RANK;
            const short8 a0 = *reinterpret_cast<const short8*>(kp);
            const short8 a1 = *reinterpret_cast<const short8*>(kp + 32);
            f32x4 z = {};
            z = MFMA16(a0, qb0, z);
            z = MFMA16(a1, qb1, z);
            short4v pk;
            #pragma unroll
            for (int r = 0; r < 4; ++r)
                pk[r] = f2b(__builtin_amdgcn_exp2f(__builtin_fmaf(z[r], cl, mC)));
            *reinterpret_cast<short4v*>(&plds[t ? pw1 : pw0]) = pk;
        }
        __syncthreads();
        short8 pa[4];
        #pragma unroll
        for (int qt = 0; qt < 4; ++qt)
            pa[qt] = *reinterpret_cast<const short8*>(&plds[a_base + qt*512]);
        #pragma unroll
        for (int dt = 0; dt < 4; ++dt) {
            const short8 vf = *reinterpret_cast<const short8*>(&vlds[b_base + dt*512]);
            #pragma unroll
            for (int qt = 0; qt < 4; ++qt)
                O[qt*4 + dt] = MFMA16(pa[qt], vf, O[qt*4 + dt]);
        }
        __syncthreads();
        if (more) {
            #pragma unroll
            for (int c = 0; c < 4; ++c)
                *reinterpret_cast<uint4*>(&vlds[st_dst + 2048*c]) = sreg[c];
        }
    }
    #pragma unroll
    for (int qt = 0; qt < 4; ++qt)
        #pragma unroll
        for (int rr = 0; rr < 4; ++rr) {
            const int q = qtile*64 + qt*16 + g*4 + rr;
            float* rowp = out + (size_t)(b*SEQ + q)*DIM + dch*256 + 64*w;
            #pragma unroll
            for (int dt = 0; dt < 4; ++dt)
                rowp[dt*16 + l15] = O[qt*4 + dt][rr];
        }
}

extern "C" void kernel_launch(void* const* d_in, const int* in_sizes, int n_in,
                              void* d_out, int out_size, void* d_ws, size_t ws_size,
                              hipStream_t stream) {
    const float* x  = (const float*)d_in[0];
    const float* Q  = (const float*)d_in[1];
    const float* K  = (const float*)d_in[2];
    const float* VO = (const float*)d_in[3];
    float* out = (float*)d_out;
    short* ws = (short*)d_ws;

    const size_t need = (P_OFF + P_LEN)*2 + (size_t)(BATCH*SEQ)*(32 + 1)*4;
    if (ws_size >= need) {
        short* Pb  = ws + P_OFF;
        short* xb  = Pb;                                   // aliases P (early)
        short* VOt = Pb + (size_t)BATCH*SEQ*DIM;
        short* Wb  = VOt + (size_t)DIM*DIM;
        float* ps  = (float*)(ws + P_OFF + P_LEN);
        float* linv = ps + (size_t)BATCH*SEQ*32;
        const hipError_t e1 = hipFuncSetAttribute(
            reinterpret_cast<const void*>(lr_pv8),
            hipFuncAttributeMaxDynamicSharedMemorySize, 131072);
        const hipError_t e2 = hipFuncSetAttribute(
            reinterpret_cast<const void*>(lr_vg8),
            hipFuncAttributeMaxDynamicSharedMemorySize, 131072);
        lr_cvt   <<<dim3(8512), dim3(256), 0, stream>>>(x, VO, Q, K, xb, VOt, Wb);
        lr_proj2 <<<dim3(128),  dim3(256), 0, stream>>>(xb, Wb, ws);
        if (e2 == hipSuccess)
            lr_vg8   <<<dim3(256), dim3(512), 131072, stream>>>(VOt, xb, ws + VT_OFF);
        else
            lr_vgemm2<<<dim3(1024), dim3(256), 0, stream>>>(VOt, xb, ws + VT_OFF);
        lr_pexp  <<<dim3(4096), dim3(256), 0, stream>>>(ws, Pb, ps);
        if (e1 == hipSuccess) {
            lr_pv8<<<dim3(256), dim3(512), 131072, stream>>>(Pb, ws + VT_OFF, ps, out);
        } else {
            lr_psum<<<dim3(64), dim3(256), 0, stream>>>(ps, linv);
            lr_pv  <<<dim3(1024), dim3(256), 0, stream>>>(Pb, ws + VT_OFF, linv, out);
        }
    } else {
        float* pm = (float*)(ws + VT_END);
        float* pl = pm + BATCH*SEQ*4;
        lr_proj <<<dim3(256),  dim3(256), 0, stream>>>(x, Q, K, ws);
        lr_stats<<<dim3(1024), dim3(256), 0, stream>>>(ws, pm, pl);
        lr_vgemm<<<dim3(1024), dim3(256), 0, stream>>>(x, VO, ws);
        lr_flash<<<dim3(1024), dim3(256), 0, stream>>>(ws, pm, pl, out);
    }
}